// Round 14
// baseline (1026.076 us; speedup 1.0000x reference)
//
#include <hip/hip_runtime.h>
#include <math.h>

#define BB 64
#define TT 128
#define SS 256
#define HHH 1024

typedef unsigned short u16;
typedef unsigned int u32;
typedef unsigned long long u64t;
typedef __bf16 bf16x8 __attribute__((ext_vector_type(8)));
typedef float f32x4 __attribute__((ext_vector_type(4)));
typedef u16 u16x8 __attribute__((ext_vector_type(8)));

__device__ __forceinline__ float sigmoidf_(float x) { return 1.0f / (1.0f + expf(-x)); }
__device__ __forceinline__ u16 f2bf(float f) {
    __bf16 h = (__bf16)f;
    return __builtin_bit_cast(u16, h);
}
__device__ __forceinline__ float b2f(u16 u) {
    return __builtin_bit_cast(float, (u32)u << 16);
}
template <typename OT>
__device__ __forceinline__ void stout(OT* p, float v) {
    if constexpr (sizeof(OT) == 2) *p = f2bf(v); else *p = v;
}
__device__ __forceinline__ void astore(u64t* p, u64t v) {
    __hip_atomic_store(p, v, __ATOMIC_RELAXED, __HIP_MEMORY_SCOPE_AGENT);
}
__device__ __forceinline__ int afetchadd(int* p) {
    return __hip_atomic_fetch_add(p, 1, __ATOMIC_RELAXED, __HIP_MEMORY_SCOPE_AGENT);
}
__device__ __forceinline__ int aload32(const int* p) {
    return __hip_atomic_load(p, __ATOMIC_RELAXED, __HIP_MEMORY_SCOPE_AGENT);
}
__device__ __forceinline__ void astore32(int* p, int v) {
    __hip_atomic_store(p, v, __ATOMIC_RELAXED, __HIP_MEMORY_SCOPE_AGENT);
}
// async global->LDS 16B copy (dest must be wave-uniform base + lane*16)
#define GLOAD16(gsrc, ldst)                                                      \
    __builtin_amdgcn_global_load_lds(                                            \
        (const __attribute__((address_space(1))) unsigned int*)(const void*)(gsrc), \
        (__attribute__((address_space(3))) unsigned int*)(void*)(ldst), 16, 0, 0)

// ---------------------------------------------------------------------------
// fused fp32 → bf16 conversions for {trg_emb, W_ih, W_in, W_out}
// grid 7680 x 256 thr x 8 elems
// ---------------------------------------------------------------------------
__global__ __launch_bounds__(256) void convert_all(
    const float* __restrict__ trg, const float* __restrict__ wih,
    const float* __restrict__ win, const float* __restrict__ wout,
    u16* __restrict__ trg16, u16* __restrict__ wih16,
    u16* __restrict__ win16, u16* __restrict__ wout16)
{
    int b = blockIdx.x;
    const float* in;
    u16* out;
    long base;
    if (b < 4096)      { in = trg;  out = trg16;  base = (long)b * 2048; }
    else if (b < 6144) { in = wih;  out = wih16;  base = (long)(b - 4096) * 2048; }
    else if (b < 6656) { in = win;  out = win16;  base = (long)(b - 6144) * 2048; }
    else               { in = wout; out = wout16; base = (long)(b - 6656) * 2048; }
    long i = base + (long)threadIdx.x * 8;
    float4 a = *(const float4*)(in + i);
    float4 c = *(const float4*)(in + i + 4);
    u16x8 o;
    o[0] = f2bf(a.x); o[1] = f2bf(a.y); o[2] = f2bf(a.z); o[3] = f2bf(a.w);
    o[4] = f2bf(c.x); o[5] = f2bf(c.y); o[6] = f2bf(c.z); o[7] = f2bf(c.w);
    *(u16x8*)(out + i) = o;
}

// ---------------------------------------------------------------------------
// W_hh fp32 -> fragment-major split-precision WF (same layout as r10-r13).
// ---------------------------------------------------------------------------
__global__ __launch_bounds__(128) void wfrag_build(const float* __restrict__ W,
                                                   u16* __restrict__ WF) {
    const int w = blockIdx.x, kq = blockIdx.y, bid = blockIdx.z;
    const int t = threadIdx.x;
    const int rh = t >> 6, lane = t & 63;
    const int rowp = bid * 32 + rh * 16 + (lane & 15);
    const int g = rowp & 3, jrow = rowp >> 2;
    const int k = kq * 256 + w * 32 + (lane >> 4) * 8;
    const float* src = W + ((size_t)(g * 1024 + jrow) << 10) + k;
    float4 v0 = *(const float4*)src;
    float4 v1 = *(const float4*)(src + 4);
    float vv[8] = {v0.x, v0.y, v0.z, v0.w, v1.x, v1.y, v1.z, v1.w};
    u16x8 hi, lo;
#pragma unroll
    for (int i = 0; i < 8; ++i) {
        u16 h = f2bf(vv[i]);
        hi[i] = h;
        lo[i] = f2bf(vv[i] - b2f(h));
    }
    size_t fr = ((((size_t)bid * 4 + kq) * 8 + w) * 2 + rh) * 2;
    *(u16x8*)(WF + fr * 512 + (size_t)lane * 8) = hi;
    *(u16x8*)(WF + (fr + 1) * 512 + (size_t)lane * 8) = lo;
}

// ---------------------------------------------------------------------------
// h0 fp32 [64 b][1024 j] -> per-GROUP fragment-major hi/lo slot (t=0 input).
// ---------------------------------------------------------------------------
__global__ __launch_bounds__(256) void h0frag(const float* __restrict__ h0,
                                              u16* __restrict__ slot) {
    int i = blockIdx.x * 256 + threadIdx.x;   // 8192 = 64 b x 128 j-groups
    int b = i >> 7, jg = i & 127;
    int j = jg << 3;
    const float* src = h0 + ((size_t)b << 10) + j;
    float4 v0 = *(const float4*)src;
    float4 v1 = *(const float4*)(src + 4);
    float vv[8] = {v0.x, v0.y, v0.z, v0.w, v1.x, v1.y, v1.z, v1.w};
    u16x8 hi, lo;
#pragma unroll
    for (int e = 0; e < 8; ++e) {
        u16 h = f2bf(vv[e]);
        hi[e] = h;
        lo[e] = f2bf(vv[e] - b2f(h));
    }
    int g = b >> 4, bl = b & 15;
    int kq = j >> 8, w = (j >> 5) & 7, tr = (j >> 3) & 3;
    int lane = tr * 16 + bl;
    size_t base = (size_t)g * 32768 + (size_t)((kq * 8 + w) * 2) * 512 + (size_t)lane * 8;
    *(u16x8*)(slot + base) = hi;
    *(u16x8*)(slot + base + 512) = lo;
}

// ---------------------------------------------------------------------------
// MFMA bf16 GEMM (A@B^T). AREMAP: logical A-row r maps to phys (r&63)*128+(r>>6)
// (xg case: r = t*64+b). BIAS adds bias0[col]+bias1[col]. C written naturally
// (coalesced): C[r][col].
// Staging via global_load_lds (16B direct-to-LDS).
// ---------------------------------------------------------------------------
template <bool TANH, bool AREMAP, bool BIAS, typename OT>
__global__ __launch_bounds__(256) void gemm_mfma_bt(
    const u16* __restrict__ A0, const u16* __restrict__ A1,
    const u16* __restrict__ B, OT* __restrict__ C,
    int M, int N, int K, int KA0,
    const float* __restrict__ bias0, const float* __restrict__ bias1)
{
    __shared__ uint4 As4[512];
    __shared__ uint4 Bs4[512];
    u16* As = (u16*)As4;
    u16* Bs = (u16*)Bs4;
    const int tid = threadIdx.x;
    const int l = tid & 63;
    const int w = tid >> 6;
    const int wm = w >> 1, wn = w & 1;
    const int tc = l & 15, tr8 = (l >> 4) << 3;
    const int m0 = blockIdx.y << 7, n0 = blockIdx.x << 7;
    f32x4 acc[4][4] = {};

    for (int k0 = 0; k0 < K; k0 += 32) {
        const u16* Ap = (k0 < KA0) ? A0 : A1;
        const int koff = (k0 < KA0) ? k0 : k0 - KA0;
#pragma unroll
        for (int r = 0; r < 2; ++r) {
            int u = tid + (r << 8);
            int row = u >> 2, q = u & 3;
            size_t arow;
            if (AREMAP) {
                int rr = m0 + row;
                arow = (size_t)((rr & 63) * 128 + (rr >> 6));
            } else {
                arow = (size_t)(m0 + row);
            }
            GLOAD16(Ap + arow * KA0 + koff + (q << 3), &As4[u]);
            GLOAD16(B + (size_t)(n0 + row) * K + k0 + (q << 3), &Bs4[u]);
        }
        __syncthreads();
        bf16x8 bfr[4];
#pragma unroll
        for (int j = 0; j < 4; ++j)
            bfr[j] = *(const bf16x8*)(Bs + ((wn << 6) + (j << 4) + tc) * 32 + tr8);
#pragma unroll
        for (int i = 0; i < 4; ++i) {
            bf16x8 af = *(const bf16x8*)(As + ((wm << 6) + (i << 4) + tc) * 32 + tr8);
#pragma unroll
            for (int j = 0; j < 4; ++j)
                acc[i][j] = __builtin_amdgcn_mfma_f32_16x16x32_bf16(af, bfr[j], acc[i][j], 0, 0, 0);
        }
        __syncthreads();
    }
#pragma unroll
    for (int j = 0; j < 4; ++j) {
        const int col = n0 + (wn << 6) + (j << 4) + tc;
        const float bias = BIAS ? (bias0[col] + bias1[col]) : 0.0f;
#pragma unroll
        for (int i = 0; i < 4; ++i) {
#pragma unroll
            for (int v = 0; v < 4; ++v) {
                int r = m0 + (wm << 6) + (i << 4) + ((l >> 4) << 2) + v;
                float val = acc[i][j][v] + bias;
                if (TANH) val = tanhf(val);
                stout(&C[(size_t)r * N + col], val);
            }
        }
    }
}

// ---------------------------------------------------------------------------
// Persistent LSTM scan v9: batch-split groups (as r13) + coalesced xg reads.
// xg layout now NATURAL: xg[t*64+b][g2*1024 + j] fp32 (bias folded).
// Epilogue thread map: ejl = tid&15 (j), ebl = tid>>4 (b) -> xgv/hT/cT loads
// and stores are lane-contiguous. Math chain identical -> bit-identical.
// ---------------------------------------------------------------------------
__global__ __launch_bounds__(512) void lstm_scan9(
    const float* __restrict__ xg, const u16* __restrict__ WF,
    const float* __restrict__ c0,
    const u16* __restrict__ h0s, u16* __restrict__ ring,
    float* __restrict__ hT, float* __restrict__ cT,
    u16* __restrict__ lstm16, int* __restrict__ bar)
{
    __shared__ float red[4][64][17];             // 17.4 KB
    __shared__ __align__(8) u16 tileh[16][16];   // [b_local][j_local]
    __shared__ __align__(8) u16 tilel[16][16];
    const int tid = threadIdx.x;
    const int bid = blockIdx.x;
    const int g = bid >> 6;            // group 0..3
    const int ib = bid & 63;           // block in group
    const int kg = tid >> 6, l = tid & 63;
    const int kq = kg & 3, rh = kg >> 2;
    const int j0 = ib << 4;            // 16 j per block
    const int ejl = tid & 15;          // epilogue local j  (coalesced axis)
    const int ebl = (tid >> 4) & 15;   // epilogue local batch (tid<256)

    // W fragments -> registers (32 frags, held for all 128 steps)
    bf16x8 wfh[2][8], wfl[2][8];
#pragma unroll
    for (int rt = 0; rt < 2; ++rt) {
        const int R16 = ib * 4 + rh * 2 + rt;
        const int bw = R16 >> 1, rhw = R16 & 1;
#pragma unroll
        for (int w = 0; w < 8; ++w) {
            size_t fr = ((((size_t)bw * 4 + kq) * 8 + w) * 2 + rhw) * 2;
            wfh[rt][w] = *(const bf16x8*)(WF + fr * 512 + (size_t)l * 8);
            wfl[rt][w] = *(const bf16x8*)(WF + (fr + 1) * 512 + (size_t)l * 8);
        }
    }
    float cv = 0.0f;
    if (tid < 256) cv = c0[(size_t)(g * 16 + ebl) * 1024 + j0 + ejl];

    // xg prefetch for t=0: row = t*64 + (g*16+ebl), col = g2*1024 + j0+ejl
    float xgv[4] = {};
    if (tid < 256) {
#pragma unroll
        for (int g2 = 0; g2 < 4; ++g2)
            xgv[g2] = xg[(size_t)(g * 16 + ebl) * 4096 + (size_t)(g2 << 10) + j0 + ejl];
    }

    const int kqs = ib >> 4, ws = (ib >> 1) & 7;   // store-frag coords
    int* const gbar = bar + (g << 9);

    for (int t = 0; t < 128; ++t) {
        const u16* hin = ((t == 0) ? h0s : (ring + (size_t)(t - 1) * 131072)) + (size_t)g * 32768;
        u16* hout = ring + (size_t)t * 131072 + (size_t)g * 32768;

        f32x4 acc[2] = {};
        bf16x8 hbA[2], hbB[2];
#define LDW(HB, W)                                                                  \
        {                                                                           \
            size_t fb = (size_t)((kq * 8 + (W)) * 2) * 512 + (size_t)l * 8;         \
            HB[0] = *(const bf16x8*)(hin + fb);                                     \
            HB[1] = *(const bf16x8*)(hin + fb + 512);                               \
        }
        LDW(hbA, 0)
#pragma unroll
        for (int w = 0; w < 8; w += 2) {
            LDW(hbB, w + 1)
#pragma unroll
            for (int rt = 0; rt < 2; ++rt) {
                acc[rt] = __builtin_amdgcn_mfma_f32_16x16x32_bf16(wfh[rt][w], hbA[0], acc[rt], 0, 0, 0);
                acc[rt] = __builtin_amdgcn_mfma_f32_16x16x32_bf16(wfh[rt][w], hbA[1], acc[rt], 0, 0, 0);
                acc[rt] = __builtin_amdgcn_mfma_f32_16x16x32_bf16(wfl[rt][w], hbA[0], acc[rt], 0, 0, 0);
            }
            if (w + 2 < 8) LDW(hbA, w + 2)
#pragma unroll
            for (int rt = 0; rt < 2; ++rt) {
                acc[rt] = __builtin_amdgcn_mfma_f32_16x16x32_bf16(wfh[rt][w + 1], hbB[0], acc[rt], 0, 0, 0);
                acc[rt] = __builtin_amdgcn_mfma_f32_16x16x32_bf16(wfh[rt][w + 1], hbB[1], acc[rt], 0, 0, 0);
                acc[rt] = __builtin_amdgcn_mfma_f32_16x16x32_bf16(wfl[rt][w + 1], hbB[0], acc[rt], 0, 0, 0);
            }
        }
#undef LDW

#pragma unroll
        for (int rt = 0; rt < 2; ++rt)
#pragma unroll
            for (int v = 0; v < 4; ++v)
                red[kq][(rh << 5) + (rt << 4) + ((l >> 4) << 2) + v][l & 15] = acc[rt][v];
        __syncthreads();

        // epilogue (tid<256): one (b_local=ebl, j_local=ejl) per thread
        if (tid < 256) {
            float gate[4];
#pragma unroll
            for (int g2 = 0; g2 < 4; ++g2) {
                int rr = (ejl << 2) + g2;
                gate[g2] = red[0][rr][ebl] + red[1][rr][ebl] +
                           red[2][rr][ebl] + red[3][rr][ebl] + xgv[g2];
            }
            float ii = sigmoidf_(gate[0]);
            float ff = sigmoidf_(gate[1]);
            float gg = tanhf(gate[2]);
            float oo = sigmoidf_(gate[3]);
            float cn = ff * cv + ii * gg;
            float hn = oo * tanhf(cn);
            cv = cn;
            u16 hh = f2bf(hn);
            tileh[ebl][ejl] = hh;
            tilel[ebl][ejl] = f2bf(hn - b2f(hh));
            if (t == 127) {
                hT[(size_t)(g * 16 + ebl) * 1024 + j0 + ejl] = hn;
                cT[(size_t)(g * 16 + ebl) * 1024 + j0 + ejl] = cn;
            }
        }
        __syncthreads();

        // store phase: group ring slot (8B atomics, frag layout) + lstm16
        if (tid < 128) {
            const int plane = tid >> 6, rem = tid & 63;
            const int b2 = rem >> 2, half = (rem >> 1) & 1, qq = rem & 1;
            const int lane = ((ib & 1) * 2 + half) * 16 + b2;
            const u16* tp = plane ? &tilel[b2][half * 8 + qq * 4] : &tileh[b2][half * 8 + qq * 4];
            size_t a16 = (size_t)(((kqs * 8 + ws) * 2 + plane)) * 512 + (size_t)lane * 8 + qq * 4;
            astore((u64t*)(hout + a16), *(const u64t*)tp);
            if (plane == 0) {
                int qj = rem & 3;
                *(u64t*)(lstm16 + ((size_t)(g * 16 + b2) * 128 + t) * 1024 + j0 + qj * 4) =
                    *(const u64t*)&tileh[b2][qj * 4];
            }
        }

        // prefetch next step's xg (independent of h) before the barrier
        if (t < 127) {
            if (tid < 256) {
#pragma unroll
                for (int g2 = 0; g2 < 4; ++g2)
                    xgv[g2] = xg[(size_t)((t + 1) * 64 + g * 16 + ebl) * 4096 +
                                 (size_t)(g2 << 10) + j0 + ejl];
            }
            __syncthreads();   // drains vmem: ring stores memory-side-visible
            if (tid == 0) {
                const int leaf = ib & 7;
                int a = afetchadd(&gbar[leaf * 16]);
                if ((a & 7) == 7) {
                    int r = afetchadd(&gbar[128]);
                    if ((r & 7) == 7) astore32(&gbar[136], t + 1);
                    while (aload32(&gbar[136]) < t + 1) __builtin_amdgcn_s_sleep(1);
                    astore32(&gbar[144 + leaf * 16], t + 1);
                } else {
                    while (aload32(&gbar[144 + leaf * 16]) < t + 1)
                        __builtin_amdgcn_s_sleep(1);
                }
            }
            __syncthreads();
        }
    }
}

// ---------------------------------------------------------------------------
// scores[b] = q[b] @ ctx[b]^T  via split-precision MFMA (fp32-equivalent).
// ---------------------------------------------------------------------------
__global__ __launch_bounds__(256) void scores_mfma(
    const float* __restrict__ q, const float* __restrict__ ctx,
    float* __restrict__ C)
{
    __shared__ u16 Ahi[4096], Alo[4096], Bhi[4096], Blo[4096];
    const int tid = threadIdx.x;
    const int l = tid & 63, w = tid >> 6;
    const int wm = w >> 1, wn = w & 1;
    const int tc = l & 15, tr8 = (l >> 4) << 3;
    const int b = blockIdx.z, n0 = blockIdx.x << 7;
    const float* A = q + (size_t)b * 131072;
    const float* B = ctx + (size_t)b * 262144;
    f32x4 acc[4][4] = {};

    for (int k0 = 0; k0 < 1024; k0 += 32) {
#pragma unroll
        for (int r = 0; r < 4; ++r) {
            int flat = r * 256 + tid;
            int row = flat >> 3, kq = (flat & 7) << 2;
            int o = row * 32 + kq;
            float4 va = *(const float4*)(A + (size_t)row * 1024 + k0 + kq);
            u16 a0 = f2bf(va.x), a1 = f2bf(va.y), a2 = f2bf(va.z), a3 = f2bf(va.w);
            *(ushort4*)&Ahi[o] = (ushort4){a0, a1, a2, a3};
            *(ushort4*)&Alo[o] = (ushort4){f2bf(va.x - b2f(a0)), f2bf(va.y - b2f(a1)),
                                           f2bf(va.z - b2f(a2)), f2bf(va.w - b2f(a3))};
            float4 vb = *(const float4*)(B + (size_t)(n0 + row) * 1024 + k0 + kq);
            u16 g0 = f2bf(vb.x), g1 = f2bf(vb.y), g2 = f2bf(vb.z), g3 = f2bf(vb.w);
            *(ushort4*)&Bhi[o] = (ushort4){g0, g1, g2, g3};
            *(ushort4*)&Blo[o] = (ushort4){f2bf(vb.x - b2f(g0)), f2bf(vb.y - b2f(g1)),
                                           f2bf(vb.z - b2f(g2)), f2bf(vb.w - b2f(g3))};
        }
        __syncthreads();
        bf16x8 bh[4], bl[4];
#pragma unroll
        for (int j = 0; j < 4; ++j) {
            int o = ((wn << 6) + (j << 4) + tc) * 32 + tr8;
            bh[j] = *(const bf16x8*)(Bhi + o);
            bl[j] = *(const bf16x8*)(Blo + o);
        }
#pragma unroll
        for (int i = 0; i < 4; ++i) {
            int o = ((wm << 6) + (i << 4) + tc) * 32 + tr8;
            bf16x8 ah = *(const bf16x8*)(Ahi + o);
            bf16x8 al = *(const bf16x8*)(Alo + o);
#pragma unroll
            for (int j = 0; j < 4; ++j) {
                acc[i][j] = __builtin_amdgcn_mfma_f32_16x16x32_bf16(ah, bh[j], acc[i][j], 0, 0, 0);
                acc[i][j] = __builtin_amdgcn_mfma_f32_16x16x32_bf16(ah, bl[j], acc[i][j], 0, 0, 0);
                acc[i][j] = __builtin_amdgcn_mfma_f32_16x16x32_bf16(al, bh[j], acc[i][j], 0, 0, 0);
            }
        }
        __syncthreads();
    }
#pragma unroll
    for (int j = 0; j < 4; ++j) {
        int col = n0 + (wn << 6) + (j << 4) + tc;
#pragma unroll
        for (int i = 0; i < 4; ++i)
#pragma unroll
            for (int v = 0; v < 4; ++v) {
                int r = (wm << 6) + (i << 4) + ((l >> 4) << 2) + v;
                C[(size_t)b * 32768 + (size_t)r * 256 + col] = acc[i][j][v];
            }
    }
}

// ---------------------------------------------------------------------------
// Masked softmax over S=256; fp32 scores -> bf16 attn.
// ---------------------------------------------------------------------------
__global__ __launch_bounds__(256) void softmax_mask16(
    const float* __restrict__ scores, const int* __restrict__ src_len,
    u16* __restrict__ attn16)
{
    __shared__ float red[4];
    const int b = blockIdx.y, t = blockIdx.x, s = threadIdx.x;
    const float* row = scores + ((long)b * TT + t) * SS;
    const int L = src_len[b];
    float v = (s < L) ? row[s] : -INFINITY;
    float m = v;
#pragma unroll
    for (int o = 32; o >= 1; o >>= 1) m = fmaxf(m, __shfl_xor(m, o));
    if ((s & 63) == 0) red[s >> 6] = m;
    __syncthreads();
    m = fmaxf(fmaxf(red[0], red[1]), fmaxf(red[2], red[3]));
    __syncthreads();
    float e = (s < L) ? expf(v - m) : 0.0f;
    float sum = e;
#pragma unroll
    for (int o = 32; o >= 1; o >>= 1) sum += __shfl_xor(sum, o);
    if ((s & 63) == 0) red[s >> 6] = sum;
    __syncthreads();
    sum = red[0] + red[1] + red[2] + red[3];
    attn16[((long)b * TT + t) * SS + s] = f2bf(e / sum);
}

// ---------------------------------------------------------------------------
// context[b] = attn[b] @ ctx[b]  via bf16 MFMA (B transposed in-LDS).
// ---------------------------------------------------------------------------
__global__ __launch_bounds__(256) void ctxattn_mfma(
    const u16* __restrict__ attn16, const float* __restrict__ ctx,
    u16* __restrict__ ctxout16)
{
    __shared__ u16 As[4096];
    __shared__ u16 Bs[128][40];
    const int tid = threadIdx.x;
    const int l = tid & 63, w = tid >> 6;
    const int wm = w >> 1, wn = w & 1;
    const int tc = l & 15, tr8 = (l >> 4) << 3;
    const int b = blockIdx.z, n0 = blockIdx.x << 7;
    f32x4 acc[4][4] = {};

    for (int k0 = 0; k0 < 256; k0 += 32) {
        {
            int row = tid >> 1, off = (tid & 1) << 4;
            const u16* src = attn16 + (size_t)b * 32768 + (size_t)row * 256 + k0 + off;
            *(uint4*)&As[row * 32 + off] = *(const uint4*)src;
            *(uint4*)&As[row * 32 + off + 8] = *(const uint4*)(src + 8);
        }
#pragma unroll
        for (int p = 0; p < 4; ++p) {
            int flat = p * 256 + tid;
            int s = flat >> 5, hc = flat & 31;
            float4 v = *(const float4*)(ctx + (size_t)b * 262144 +
                                        (size_t)(k0 + s) * 1024 + n0 + (hc << 2));
            Bs[(hc << 2) + 0][s] = f2bf(v.x);
            Bs[(hc << 2) + 1][s] = f2bf(v.y);
            Bs[(hc << 2) + 2][s] = f2bf(v.z);
            Bs[(hc << 2) + 3][s] = f2bf(v.w);
        }
        __syncthreads();
        bf16x8 bfr[4];
#pragma unroll
        for (int j = 0; j < 4; ++j)
            bfr[j] = *(const bf16x8*)&Bs[(wn << 6) + (j << 4) + tc][tr8];
#pragma unroll
        for (int i = 0; i < 4; ++i) {
            bf16x8 af = *(const bf16x8*)(As + ((wm << 6) + (i << 4) + tc) * 32 + tr8);
#pragma unroll
            for (int j = 0; j < 4; ++j)
                acc[i][j] = __builtin_amdgcn_mfma_f32_16x16x32_bf16(af, bfr[j], acc[i][j], 0, 0, 0);
        }
        __syncthreads();
    }
#pragma unroll
    for (int j = 0; j < 4; ++j) {
        int col = n0 + (wn << 6) + (j << 4) + tc;
#pragma unroll
        for (int i = 0; i < 4; ++i)
#pragma unroll
            for (int v = 0; v < 4; ++v) {
                int r = (wm << 6) + (i << 4) + ((l >> 4) << 2) + v;
                ctxout16[((size_t)b * 128 + r) * 1024 + col] = f2bf(acc[i][j][v]);
            }
    }
}

// ---------------------------------------------------------------------------
extern "C" void kernel_launch(void* const* d_in, const int* in_sizes, int n_in,
                              void* d_out, int out_size, void* d_ws, size_t ws_size,
                              hipStream_t stream)
{
    const float* trg_emb = (const float*)d_in[0];
    const float* h0      = (const float*)d_in[1];
    const float* c0      = (const float*)d_in[2];
    const float* ctx     = (const float*)d_in[3];
    const int*   src_len = (const int*)d_in[4];
    const float* W_ih    = (const float*)d_in[5];
    const float* W_hh    = (const float*)d_in[6];
    const float* b_ih    = (const float*)d_in[7];
    const float* b_hh    = (const float*)d_in[8];
    const float* W_in    = (const float*)d_in[9];
    const float* W_out   = (const float*)d_in[10];

    float* out = (float*)d_out;
    float* h_tilde = out;                          // [B,T,H]
    float* hT = out + (size_t)BB * TT * HHH;       // [1,B,H]
    float* cT = hT + (size_t)BB * HHH;             // [1,B,H]

    char* w = (char*)d_ws;
    auto take = [&](size_t bytes) { void* p = w; w += (bytes + 255) & ~(size_t)255; return p; };
    // ring (128 slots x 256 KB = 33.55 MB) aliases trg16+Wih16+spare (safe:
    // ring written only inside lstm_scan9, after the xg GEMM — stream order).
    char* base0 = w;
    u16* trg16  = (u16*)take(8388608ull * 2);      // 16.78 MB
    u16* Wih16  = (u16*)take(4194304ull * 2);      //  8.39 MB
    take(8388608ull);                              //  8.39 MB ring tail spare
    u16* ring   = (u16*)base0;                     // 33.55 MB total
    u16* h0s    = (u16*)take(262144ull);           // 4-group frag slot for t=0
    u16* Win16  = (u16*)take(1048576ull * 2);
    u16* Wout16 = (u16*)take(2097152ull * 2);
    u16* lstm16 = (u16*)take(8388608ull * 2);
    u16* WF     = (u16*)take(16777216ull);         // W fragment layout
    int* bar    = (int*)take(8192);
    char* regionB = w;
    float* xg = (float*)take(33554432ull * 4);     // [t*64+b][4096] fp32, bias folded
    float* q        = (float*)regionB;                          // 33.55 MB
    float* scores   = (float*)(regionB + 33554432ull);          //  8.39 MB
    u16*   attn16   = (u16*)(regionB + 41943040ull);            //  4.19 MB
    u16*   ctxout16 = (u16*)(regionB + 46137344ull);            // 16.78 MB

    // barrier counters must start at 0 every call
    hipMemsetAsync(bar, 0, 8192, stream);

    // prep (fused conversions + frag builds)
    convert_all<<<7680, 256, 0, stream>>>(trg_emb, W_ih, W_in, W_out,
                                          trg16, Wih16, Win16, Wout16);
    wfrag_build<<<dim3(8, 4, 128), 128, 0, stream>>>(W_hh, WF);
    h0frag<<<32, 256, 0, stream>>>(h0, h0s);

    // x_gates = trg_emb @ W_ih^T + (b_ih+b_hh) -> fp32 xg[t*64+b][4096]
    // (A-rows remapped so logical r = t*64+b; C written naturally/coalesced)
    gemm_mfma_bt<false, true, true, float><<<dim3(32, 64), 256, 0, stream>>>(
        trg16, trg16, Wih16, xg, 8192, 4096, 1024, 1024, b_ih, b_hh);

    // persistent LSTM scan (single launch; writes lstm16, hT, cT)
    lstm_scan9<<<256, 512, 0, stream>>>(xg, WF, c0, h0s, ring,
                                        hT, cT, lstm16, bar);

    // q = lstm_out @ W_in^T (bf16 MFMA, fp32 out)
    gemm_mfma_bt<false, false, false, float><<<dim3(8, 64), 256, 0, stream>>>(
        lstm16, lstm16, Win16, q, 8192, 1024, 1024, 1024, nullptr, nullptr);

    // scores[b] = q[b] @ ctx[b]^T (split-precision MFMA, fp32-equivalent)
    scores_mfma<<<dim3(2, 1, 64), 256, 0, stream>>>(q, ctx, scores);

    // masked softmax -> bf16 attention weights
    softmax_mask16<<<dim3(TT, BB, 1), 256, 0, stream>>>(scores, src_len, attn16);

    // context[b] = attn[b] @ ctx[b] (bf16 MFMA, bf16 out)
    ctxattn_mfma<<<dim3(8, 1, 64), 256, 0, stream>>>(attn16, ctx, ctxout16);

    // h_tilde = tanh([context, lstm_out] @ W_out^T)
    gemm_mfma_bt<true, false, false, float><<<dim3(8, 64), 256, 0, stream>>>(
        ctxout16, lstm16, Wout16, h_tilde, 8192, 1024, 2048, 1024, nullptr, nullptr);
}

// Round 15
// 1014.731 us; speedup vs baseline: 1.0112x; 1.0112x over previous
//
#include <hip/hip_runtime.h>
#include <math.h>

#define BB 64
#define TT 128
#define SS 256
#define HHH 1024

typedef unsigned short u16;
typedef unsigned int u32;
typedef unsigned long long u64t;
typedef __bf16 bf16x8 __attribute__((ext_vector_type(8)));
typedef float f32x4 __attribute__((ext_vector_type(4)));
typedef u16 u16x8 __attribute__((ext_vector_type(8)));

__device__ __forceinline__ float sigmoidf_(float x) { return 1.0f / (1.0f + expf(-x)); }
__device__ __forceinline__ u16 f2bf(float f) {
    __bf16 h = (__bf16)f;
    return __builtin_bit_cast(u16, h);
}
__device__ __forceinline__ float b2f(u16 u) {
    return __builtin_bit_cast(float, (u32)u << 16);
}
template <typename OT>
__device__ __forceinline__ void stout(OT* p, float v) {
    if constexpr (sizeof(OT) == 2) *p = f2bf(v); else *p = v;
}
__device__ __forceinline__ void astore(u64t* p, u64t v) {
    __hip_atomic_store(p, v, __ATOMIC_RELAXED, __HIP_MEMORY_SCOPE_AGENT);
}
__device__ __forceinline__ int afetchadd(int* p) {
    return __hip_atomic_fetch_add(p, 1, __ATOMIC_RELAXED, __HIP_MEMORY_SCOPE_AGENT);
}
__device__ __forceinline__ int aload32(const int* p) {
    return __hip_atomic_load(p, __ATOMIC_RELAXED, __HIP_MEMORY_SCOPE_AGENT);
}
__device__ __forceinline__ void astore32(int* p, int v) {
    __hip_atomic_store(p, v, __ATOMIC_RELAXED, __HIP_MEMORY_SCOPE_AGENT);
}
// async global->LDS 16B copy (dest must be wave-uniform base + lane*16)
#define GLOAD16(gsrc, ldst)                                                      \
    __builtin_amdgcn_global_load_lds(                                            \
        (const __attribute__((address_space(1))) unsigned int*)(const void*)(gsrc), \
        (__attribute__((address_space(3))) unsigned int*)(void*)(ldst), 16, 0, 0)

// ---------------------------------------------------------------------------
// fused fp32 → bf16 conversions for {trg_emb, W_ih, W_in, W_out}
// ---------------------------------------------------------------------------
__global__ __launch_bounds__(256) void convert_all(
    const float* __restrict__ trg, const float* __restrict__ wih,
    const float* __restrict__ win, const float* __restrict__ wout,
    u16* __restrict__ trg16, u16* __restrict__ wih16,
    u16* __restrict__ win16, u16* __restrict__ wout16)
{
    int b = blockIdx.x;
    const float* in;
    u16* out;
    long base;
    if (b < 4096)      { in = trg;  out = trg16;  base = (long)b * 2048; }
    else if (b < 6144) { in = wih;  out = wih16;  base = (long)(b - 4096) * 2048; }
    else if (b < 6656) { in = win;  out = win16;  base = (long)(b - 6144) * 2048; }
    else               { in = wout; out = wout16; base = (long)(b - 6656) * 2048; }
    long i = base + (long)threadIdx.x * 8;
    float4 a = *(const float4*)(in + i);
    float4 c = *(const float4*)(in + i + 4);
    u16x8 o;
    o[0] = f2bf(a.x); o[1] = f2bf(a.y); o[2] = f2bf(a.z); o[3] = f2bf(a.w);
    o[4] = f2bf(c.x); o[5] = f2bf(c.y); o[6] = f2bf(c.z); o[7] = f2bf(c.w);
    *(u16x8*)(out + i) = o;
}

// ---------------------------------------------------------------------------
// W_hh fp32 -> fragment-major split-precision WF (same layout as r10-r13).
// ---------------------------------------------------------------------------
__global__ __launch_bounds__(128) void wfrag_build(const float* __restrict__ W,
                                                   u16* __restrict__ WF) {
    const int w = blockIdx.x, kq = blockIdx.y, bid = blockIdx.z;
    const int t = threadIdx.x;
    const int rh = t >> 6, lane = t & 63;
    const int rowp = bid * 32 + rh * 16 + (lane & 15);
    const int g = rowp & 3, jrow = rowp >> 2;
    const int k = kq * 256 + w * 32 + (lane >> 4) * 8;
    const float* src = W + ((size_t)(g * 1024 + jrow) << 10) + k;
    float4 v0 = *(const float4*)src;
    float4 v1 = *(const float4*)(src + 4);
    float vv[8] = {v0.x, v0.y, v0.z, v0.w, v1.x, v1.y, v1.z, v1.w};
    u16x8 hi, lo;
#pragma unroll
    for (int i = 0; i < 8; ++i) {
        u16 h = f2bf(vv[i]);
        hi[i] = h;
        lo[i] = f2bf(vv[i] - b2f(h));
    }
    size_t fr = ((((size_t)bid * 4 + kq) * 8 + w) * 2 + rh) * 2;
    *(u16x8*)(WF + fr * 512 + (size_t)lane * 8) = hi;
    *(u16x8*)(WF + (fr + 1) * 512 + (size_t)lane * 8) = lo;
}

// ---------------------------------------------------------------------------
// h0 fp32 [64 b][1024 j] -> per-GROUP fragment-major hi/lo slot (t=0 input).
// ---------------------------------------------------------------------------
__global__ __launch_bounds__(256) void h0frag(const float* __restrict__ h0,
                                              u16* __restrict__ slot) {
    int i = blockIdx.x * 256 + threadIdx.x;   // 8192 = 64 b x 128 j-groups
    int b = i >> 7, jg = i & 127;
    int j = jg << 3;
    const float* src = h0 + ((size_t)b << 10) + j;
    float4 v0 = *(const float4*)src;
    float4 v1 = *(const float4*)(src + 4);
    float vv[8] = {v0.x, v0.y, v0.z, v0.w, v1.x, v1.y, v1.z, v1.w};
    u16x8 hi, lo;
#pragma unroll
    for (int e = 0; e < 8; ++e) {
        u16 h = f2bf(vv[e]);
        hi[e] = h;
        lo[e] = f2bf(vv[e] - b2f(h));
    }
    int g = b >> 4, bl = b & 15;
    int kq = j >> 8, w = (j >> 5) & 7, tr = (j >> 3) & 3;
    int lane = tr * 16 + bl;
    size_t base = (size_t)g * 32768 + (size_t)((kq * 8 + w) * 2) * 512 + (size_t)lane * 8;
    *(u16x8*)(slot + base) = hi;
    *(u16x8*)(slot + base + 512) = lo;
}

// ---------------------------------------------------------------------------
// MFMA bf16 GEMM (A@B^T). XGT mode: logical A row r=t*64+b (phys (r&63)*128+(r>>6));
// C written fp32 to xgt[t][j*4+g][b] with (b_ih+b_hh) folded. (r13 layout)
// ---------------------------------------------------------------------------
template <bool TANH, bool XGT, typename OT>
__global__ __launch_bounds__(256) void gemm_mfma_bt(
    const u16* __restrict__ A0, const u16* __restrict__ A1,
    const u16* __restrict__ B, OT* __restrict__ C,
    int M, int N, int K, int KA0,
    const float* __restrict__ bias0, const float* __restrict__ bias1)
{
    __shared__ uint4 As4[512];
    __shared__ uint4 Bs4[512];
    u16* As = (u16*)As4;
    u16* Bs = (u16*)Bs4;
    const int tid = threadIdx.x;
    const int l = tid & 63;
    const int w = tid >> 6;
    const int wm = w >> 1, wn = w & 1;
    const int tc = l & 15, tr8 = (l >> 4) << 3;
    const int m0 = blockIdx.y << 7, n0 = blockIdx.x << 7;
    f32x4 acc[4][4] = {};

    for (int k0 = 0; k0 < K; k0 += 32) {
        const u16* Ap = (k0 < KA0) ? A0 : A1;
        const int koff = (k0 < KA0) ? k0 : k0 - KA0;
#pragma unroll
        for (int r = 0; r < 2; ++r) {
            int u = tid + (r << 8);
            int row = u >> 2, q = u & 3;
            size_t arow;
            if (XGT) {
                int rr = m0 + row;
                arow = (size_t)((rr & 63) * 128 + (rr >> 6));
            } else {
                arow = (size_t)(m0 + row);
            }
            GLOAD16(Ap + arow * KA0 + koff + (q << 3), &As4[u]);
            GLOAD16(B + (size_t)(n0 + row) * K + k0 + (q << 3), &Bs4[u]);
        }
        __syncthreads();
        bf16x8 bfr[4];
#pragma unroll
        for (int j = 0; j < 4; ++j)
            bfr[j] = *(const bf16x8*)(Bs + ((wn << 6) + (j << 4) + tc) * 32 + tr8);
#pragma unroll
        for (int i = 0; i < 4; ++i) {
            bf16x8 af = *(const bf16x8*)(As + ((wm << 6) + (i << 4) + tc) * 32 + tr8);
#pragma unroll
            for (int j = 0; j < 4; ++j)
                acc[i][j] = __builtin_amdgcn_mfma_f32_16x16x32_bf16(af, bfr[j], acc[i][j], 0, 0, 0);
        }
        __syncthreads();
    }
#pragma unroll
    for (int j = 0; j < 4; ++j) {
        const int col = n0 + (wn << 6) + (j << 4) + tc;
        const float bias = XGT ? (bias0[col] + bias1[col]) : 0.0f;
#pragma unroll
        for (int i = 0; i < 4; ++i) {
#pragma unroll
            for (int v = 0; v < 4; ++v) {
                int r = m0 + (wm << 6) + (i << 4) + ((l >> 4) << 2) + v;
                float val = acc[i][j][v];
                if (XGT) {
                    int newr = ((col & 1023) << 2) | (col >> 10);   // j*4+g
                    ((float*)C)[(size_t)(r >> 6) * 262144 + (size_t)newr * 64 + (r & 63)] = val + bias;
                } else {
                    if (TANH) val = tanhf(val);
                    stout(&C[(size_t)r * N + col], val);
                }
            }
        }
    }
}

// ---------------------------------------------------------------------------
// Persistent LSTM scan v10 = r13's scan8 + early-issued double-buffered xgv.
// 4 groups x 64 blocks; block owns 16 j x 4 gates for its group's 16 batches.
// xgv for step t+1 is issued at the TOP of step t (T14 issue-early): by the
// pre-barrier vmcnt drain those loads are long complete, so the drain waits
// only on the ring atomic stores. Math chain identical -> bit-identical.
// ---------------------------------------------------------------------------
__global__ __launch_bounds__(512) void lstm_scan10(
    const float* __restrict__ xgt, const u16* __restrict__ WF,
    const float* __restrict__ c0,
    const u16* __restrict__ h0s, u16* __restrict__ ring,
    float* __restrict__ hT, float* __restrict__ cT,
    u16* __restrict__ lstm16, int* __restrict__ bar)
{
    __shared__ float red[4][64][17];             // 17.4 KB
    __shared__ __align__(8) u16 tileh[16][16];   // [b_local][j_local]
    __shared__ __align__(8) u16 tilel[16][16];
    const int tid = threadIdx.x;
    const int bid = blockIdx.x;
    const int g = bid >> 6;            // group 0..3
    const int ib = bid & 63;           // block in group
    const int kg = tid >> 6, l = tid & 63;
    const int kq = kg & 3, rh = kg >> 2;
    const int j0 = ib << 4;            // 16 j per block
    const int ebl = tid & 15;          // epilogue local batch
    const int ejl = (tid >> 4) & 15;   // epilogue local j (tid<256)

    // W fragments -> registers (32 frags, held for all 128 steps)
    bf16x8 wfh[2][8], wfl[2][8];
#pragma unroll
    for (int rt = 0; rt < 2; ++rt) {
        const int R16 = ib * 4 + rh * 2 + rt;
        const int bw = R16 >> 1, rhw = R16 & 1;
#pragma unroll
        for (int w = 0; w < 8; ++w) {
            size_t fr = ((((size_t)bw * 4 + kq) * 8 + w) * 2 + rhw) * 2;
            wfh[rt][w] = *(const bf16x8*)(WF + fr * 512 + (size_t)l * 8);
            wfl[rt][w] = *(const bf16x8*)(WF + (fr + 1) * 512 + (size_t)l * 8);
        }
    }
    float cv = 0.0f;
    if (tid < 256) cv = c0[(size_t)(g * 16 + ebl) * 1024 + j0 + ejl];

    // xgv double buffer: A = current step, B = next step (issued early)
    float xgvA[4] = {}, xgvB[4] = {};
    if (tid < 256) {
#pragma unroll
        for (int g2 = 0; g2 < 4; ++g2)
            xgvA[g2] = xgt[(size_t)(((j0 + ejl) << 2) + g2) * 64 + g * 16 + ebl];
    }

    const int kqs = ib >> 4, ws = (ib >> 1) & 7;   // store-frag coords
    int* const gbar = bar + (g << 9);

    for (int t = 0; t < 128; ++t) {
        const u16* hin = ((t == 0) ? h0s : (ring + (size_t)(t - 1) * 131072)) + (size_t)g * 32768;
        u16* hout = ring + (size_t)t * 131072 + (size_t)g * 32768;

        // EARLY issue of next step's xgt loads (independent of h; completes
        // during the MFMA phase, so the pre-barrier drain doesn't stall on it)
        if (t < 127 && tid < 256) {
#pragma unroll
            for (int g2 = 0; g2 < 4; ++g2)
                xgvB[g2] = xgt[(size_t)(t + 1) * 262144 +
                               (size_t)(((j0 + ejl) << 2) + g2) * 64 + g * 16 + ebl];
        }

        f32x4 acc[2] = {};
        bf16x8 hbA[2], hbB[2];
#define LDW(HB, W)                                                                  \
        {                                                                           \
            size_t fb = (size_t)((kq * 8 + (W)) * 2) * 512 + (size_t)l * 8;         \
            HB[0] = *(const bf16x8*)(hin + fb);                                     \
            HB[1] = *(const bf16x8*)(hin + fb + 512);                               \
        }
        LDW(hbA, 0)
#pragma unroll
        for (int w = 0; w < 8; w += 2) {
            LDW(hbB, w + 1)
#pragma unroll
            for (int rt = 0; rt < 2; ++rt) {
                acc[rt] = __builtin_amdgcn_mfma_f32_16x16x32_bf16(wfh[rt][w], hbA[0], acc[rt], 0, 0, 0);
                acc[rt] = __builtin_amdgcn_mfma_f32_16x16x32_bf16(wfh[rt][w], hbA[1], acc[rt], 0, 0, 0);
                acc[rt] = __builtin_amdgcn_mfma_f32_16x16x32_bf16(wfl[rt][w], hbA[0], acc[rt], 0, 0, 0);
            }
            if (w + 2 < 8) LDW(hbA, w + 2)
#pragma unroll
            for (int rt = 0; rt < 2; ++rt) {
                acc[rt] = __builtin_amdgcn_mfma_f32_16x16x32_bf16(wfh[rt][w + 1], hbB[0], acc[rt], 0, 0, 0);
                acc[rt] = __builtin_amdgcn_mfma_f32_16x16x32_bf16(wfh[rt][w + 1], hbB[1], acc[rt], 0, 0, 0);
                acc[rt] = __builtin_amdgcn_mfma_f32_16x16x32_bf16(wfl[rt][w + 1], hbB[0], acc[rt], 0, 0, 0);
            }
        }
#undef LDW

#pragma unroll
        for (int rt = 0; rt < 2; ++rt)
#pragma unroll
            for (int v = 0; v < 4; ++v)
                red[kq][(rh << 5) + (rt << 4) + ((l >> 4) << 2) + v][l & 15] = acc[rt][v];
        __syncthreads();

        // epilogue (tid<256): one (b_local=ebl, j_local=ejl) per thread
        if (tid < 256) {
            float gate[4];
#pragma unroll
            for (int g2 = 0; g2 < 4; ++g2) {
                int rr = (ejl << 2) + g2;
                gate[g2] = red[0][rr][ebl] + red[1][rr][ebl] +
                           red[2][rr][ebl] + red[3][rr][ebl] + xgvA[g2];
            }
            float ii = sigmoidf_(gate[0]);
            float ff = sigmoidf_(gate[1]);
            float gg = tanhf(gate[2]);
            float oo = sigmoidf_(gate[3]);
            float cn = ff * cv + ii * gg;
            float hn = oo * tanhf(cn);
            cv = cn;
            u16 hh = f2bf(hn);
            tileh[ebl][ejl] = hh;
            tilel[ebl][ejl] = f2bf(hn - b2f(hh));
            if (t == 127) {
                hT[(size_t)(g * 16 + ebl) * 1024 + j0 + ejl] = hn;
                cT[(size_t)(g * 16 + ebl) * 1024 + j0 + ejl] = cn;
            }
        }
        __syncthreads();

        // store phase: group ring slot (8B atomics, frag layout) + lstm16
        if (tid < 128) {
            const int plane = tid >> 6, rem = tid & 63;
            const int b2 = rem >> 2, half = (rem >> 1) & 1, qq = rem & 1;
            const int lane = ((ib & 1) * 2 + half) * 16 + b2;
            const u16* tp = plane ? &tilel[b2][half * 8 + qq * 4] : &tileh[b2][half * 8 + qq * 4];
            size_t a16 = (size_t)(((kqs * 8 + ws) * 2 + plane)) * 512 + (size_t)lane * 8 + qq * 4;
            astore((u64t*)(hout + a16), *(const u64t*)tp);
            if (plane == 0) {
                int qj = rem & 3;
                *(u64t*)(lstm16 + ((size_t)(g * 16 + b2) * 128 + t) * 1024 + j0 + qj * 4) =
                    *(const u64t*)&tileh[b2][qj * 4];
            }
        }

        // group-local hierarchical barrier (pre-barrier drain now covers only
        // the ring stores; xgvB loads completed during the MFMA phase)
        if (t < 127) {
            __syncthreads();
            if (tid == 0) {
                const int leaf = ib & 7;
                int a = afetchadd(&gbar[leaf * 16]);
                if ((a & 7) == 7) {
                    int r = afetchadd(&gbar[128]);
                    if ((r & 7) == 7) astore32(&gbar[136], t + 1);
                    while (aload32(&gbar[136]) < t + 1) __builtin_amdgcn_s_sleep(1);
                    astore32(&gbar[144 + leaf * 16], t + 1);
                } else {
                    while (aload32(&gbar[144 + leaf * 16]) < t + 1)
                        __builtin_amdgcn_s_sleep(1);
                }
            }
            __syncthreads();
#pragma unroll
            for (int g2 = 0; g2 < 4; ++g2) xgvA[g2] = xgvB[g2];
        }
    }
}

// ---------------------------------------------------------------------------
// scores[b] = q[b] @ ctx[b]^T  via split-precision MFMA (fp32-equivalent).
// ---------------------------------------------------------------------------
__global__ __launch_bounds__(256) void scores_mfma(
    const float* __restrict__ q, const float* __restrict__ ctx,
    float* __restrict__ C)
{
    __shared__ u16 Ahi[4096], Alo[4096], Bhi[4096], Blo[4096];
    const int tid = threadIdx.x;
    const int l = tid & 63, w = tid >> 6;
    const int wm = w >> 1, wn = w & 1;
    const int tc = l & 15, tr8 = (l >> 4) << 3;
    const int b = blockIdx.z, n0 = blockIdx.x << 7;
    const float* A = q + (size_t)b * 131072;
    const float* B = ctx + (size_t)b * 262144;
    f32x4 acc[4][4] = {};

    for (int k0 = 0; k0 < 1024; k0 += 32) {
#pragma unroll
        for (int r = 0; r < 4; ++r) {
            int flat = r * 256 + tid;
            int row = flat >> 3, kq = (flat & 7) << 2;
            int o = row * 32 + kq;
            float4 va = *(const float4*)(A + (size_t)row * 1024 + k0 + kq);
            u16 a0 = f2bf(va.x), a1 = f2bf(va.y), a2 = f2bf(va.z), a3 = f2bf(va.w);
            *(ushort4*)&Ahi[o] = (ushort4){a0, a1, a2, a3};
            *(ushort4*)&Alo[o] = (ushort4){f2bf(va.x - b2f(a0)), f2bf(va.y - b2f(a1)),
                                           f2bf(va.z - b2f(a2)), f2bf(va.w - b2f(a3))};
            float4 vb = *(const float4*)(B + (size_t)(n0 + row) * 1024 + k0 + kq);
            u16 g0 = f2bf(vb.x), g1 = f2bf(vb.y), g2 = f2bf(vb.z), g3 = f2bf(vb.w);
            *(ushort4*)&Bhi[o] = (ushort4){g0, g1, g2, g3};
            *(ushort4*)&Blo[o] = (ushort4){f2bf(vb.x - b2f(g0)), f2bf(vb.y - b2f(g1)),
                                           f2bf(vb.z - b2f(g2)), f2bf(vb.w - b2f(g3))};
        }
        __syncthreads();
        bf16x8 bh[4], bl[4];
#pragma unroll
        for (int j = 0; j < 4; ++j) {
            int o = ((wn << 6) + (j << 4) + tc) * 32 + tr8;
            bh[j] = *(const bf16x8*)(Bhi + o);
            bl[j] = *(const bf16x8*)(Blo + o);
        }
#pragma unroll
        for (int i = 0; i < 4; ++i) {
            int o = ((wm << 6) + (i << 4) + tc) * 32 + tr8;
            bf16x8 ah = *(const bf16x8*)(Ahi + o);
            bf16x8 al = *(const bf16x8*)(Alo + o);
#pragma unroll
            for (int j = 0; j < 4; ++j) {
                acc[i][j] = __builtin_amdgcn_mfma_f32_16x16x32_bf16(ah, bh[j], acc[i][j], 0, 0, 0);
                acc[i][j] = __builtin_amdgcn_mfma_f32_16x16x32_bf16(ah, bl[j], acc[i][j], 0, 0, 0);
                acc[i][j] = __builtin_amdgcn_mfma_f32_16x16x32_bf16(al, bh[j], acc[i][j], 0, 0, 0);
            }
        }
        __syncthreads();
    }
#pragma unroll
    for (int j = 0; j < 4; ++j) {
        int col = n0 + (wn << 6) + (j << 4) + tc;
#pragma unroll
        for (int i = 0; i < 4; ++i)
#pragma unroll
            for (int v = 0; v < 4; ++v) {
                int r = (wm << 6) + (i << 4) + ((l >> 4) << 2) + v;
                C[(size_t)b * 32768 + (size_t)r * 256 + col] = acc[i][j][v];
            }
    }
}

// ---------------------------------------------------------------------------
// Masked softmax over S=256; fp32 scores -> bf16 attn.
// ---------------------------------------------------------------------------
__global__ __launch_bounds__(256) void softmax_mask16(
    const float* __restrict__ scores, const int* __restrict__ src_len,
    u16* __restrict__ attn16)
{
    __shared__ float red[4];
    const int b = blockIdx.y, t = blockIdx.x, s = threadIdx.x;
    const float* row = scores + ((long)b * TT + t) * SS;
    const int L = src_len[b];
    float v = (s < L) ? row[s] : -INFINITY;
    float m = v;
#pragma unroll
    for (int o = 32; o >= 1; o >>= 1) m = fmaxf(m, __shfl_xor(m, o));
    if ((s & 63) == 0) red[s >> 6] = m;
    __syncthreads();
    m = fmaxf(fmaxf(red[0], red[1]), fmaxf(red[2], red[3]));
    __syncthreads();
    float e = (s < L) ? expf(v - m) : 0.0f;
    float sum = e;
#pragma unroll
    for (int o = 32; o >= 1; o >>= 1) sum += __shfl_xor(sum, o);
    if ((s & 63) == 0) red[s >> 6] = sum;
    __syncthreads();
    sum = red[0] + red[1] + red[2] + red[3];
    attn16[((long)b * TT + t) * SS + s] = f2bf(e / sum);
}

// ---------------------------------------------------------------------------
// context[b] = attn[b] @ ctx[b]  via bf16 MFMA (B transposed in-LDS).
// ---------------------------------------------------------------------------
__global__ __launch_bounds__(256) void ctxattn_mfma(
    const u16* __restrict__ attn16, const float* __restrict__ ctx,
    u16* __restrict__ ctxout16)
{
    __shared__ u16 As[4096];
    __shared__ u16 Bs[128][40];
    const int tid = threadIdx.x;
    const int l = tid & 63, w = tid >> 6;
    const int wm = w >> 1, wn = w & 1;
    const int tc = l & 15, tr8 = (l >> 4) << 3;
    const int b = blockIdx.z, n0 = blockIdx.x << 7;
    f32x4 acc[4][4] = {};

    for (int k0 = 0; k0 < 256; k0 += 32) {
        {
            int row = tid >> 1, off = (tid & 1) << 4;
            const u16* src = attn16 + (size_t)b * 32768 + (size_t)row * 256 + k0 + off;
            *(uint4*)&As[row * 32 + off] = *(const uint4*)src;
            *(uint4*)&As[row * 32 + off + 8] = *(const uint4*)(src + 8);
        }
#pragma unroll
        for (int p = 0; p < 4; ++p) {
            int flat = p * 256 + tid;
            int s = flat >> 5, hc = flat & 31;
            float4 v = *(const float4*)(ctx + (size_t)b * 262144 +
                                        (size_t)(k0 + s) * 1024 + n0 + (hc << 2));
            Bs[(hc << 2) + 0][s] = f2bf(v.x);
            Bs[(hc << 2) + 1][s] = f2bf(v.y);
            Bs[(hc << 2) + 2][s] = f2bf(v.z);
            Bs[(hc << 2) + 3][s] = f2bf(v.w);
        }
        __syncthreads();
        bf16x8 bfr[4];
#pragma unroll
        for (int j = 0; j < 4; ++j)
            bfr[j] = *(const bf16x8*)&Bs[(wn << 6) + (j << 4) + tc][tr8];
#pragma unroll
        for (int i = 0; i < 4; ++i) {
            bf16x8 af = *(const bf16x8*)(As + ((wm << 6) + (i << 4) + tc) * 32 + tr8);
#pragma unroll
            for (int j = 0; j < 4; ++j)
                acc[i][j] = __builtin_amdgcn_mfma_f32_16x16x32_bf16(af, bfr[j], acc[i][j], 0, 0, 0);
        }
        __syncthreads();
    }
#pragma unroll
    for (int j = 0; j < 4; ++j) {
        int col = n0 + (wn << 6) + (j << 4) + tc;
#pragma unroll
        for (int i = 0; i < 4; ++i)
#pragma unroll
            for (int v = 0; v < 4; ++v) {
                int r = (wm << 6) + (i << 4) + ((l >> 4) << 2) + v;
                ctxout16[((size_t)b * 128 + r) * 1024 + col] = f2bf(acc[i][j][v]);
            }
    }
}

// ---------------------------------------------------------------------------
extern "C" void kernel_launch(void* const* d_in, const int* in_sizes, int n_in,
                              void* d_out, int out_size, void* d_ws, size_t ws_size,
                              hipStream_t stream)
{
    const float* trg_emb = (const float*)d_in[0];
    const float* h0      = (const float*)d_in[1];
    const float* c0      = (const float*)d_in[2];
    const float* ctx     = (const float*)d_in[3];
    const int*   src_len = (const int*)d_in[4];
    const float* W_ih    = (const float*)d_in[5];
    const float* W_hh    = (const float*)d_in[6];
    const float* b_ih    = (const float*)d_in[7];
    const float* b_hh    = (const float*)d_in[8];
    const float* W_in    = (const float*)d_in[9];
    const float* W_out   = (const float*)d_in[10];

    float* out = (float*)d_out;
    float* h_tilde = out;                          // [B,T,H]
    float* hT = out + (size_t)BB * TT * HHH;       // [1,B,H]
    float* cT = hT + (size_t)BB * HHH;             // [1,B,H]

    char* w = (char*)d_ws;
    auto take = [&](size_t bytes) { void* p = w; w += (bytes + 255) & ~(size_t)255; return p; };
    // ring (128 slots x 256 KB = 33.55 MB) aliases trg16+Wih16+spare (safe:
    // ring written only inside lstm_scan10, after the xgt GEMM — stream order).
    char* base0 = w;
    u16* trg16  = (u16*)take(8388608ull * 2);      // 16.78 MB
    u16* Wih16  = (u16*)take(4194304ull * 2);      //  8.39 MB
    take(8388608ull);                              //  8.39 MB ring tail spare
    u16* ring   = (u16*)base0;                     // 33.55 MB total
    u16* h0s    = (u16*)take(262144ull);           // 4-group frag slot for t=0
    u16* Win16  = (u16*)take(1048576ull * 2);
    u16* Wout16 = (u16*)take(2097152ull * 2);
    u16* lstm16 = (u16*)take(8388608ull * 2);
    u16* WF     = (u16*)take(16777216ull);         // W fragment layout
    int* bar    = (int*)take(8192);
    char* regionB = w;
    float* xgt = (float*)take(33554432ull * 4);    // [t][4H r=j*4+g][B] fp32
    float* q        = (float*)regionB;                          // 33.55 MB
    float* scores   = (float*)(regionB + 33554432ull);          //  8.39 MB
    u16*   attn16   = (u16*)(regionB + 41943040ull);            //  4.19 MB
    u16*   ctxout16 = (u16*)(regionB + 46137344ull);            // 16.78 MB

    // barrier counters must start at 0 every call
    hipMemsetAsync(bar, 0, 8192, stream);

    // prep (fused conversions + frag builds)
    convert_all<<<7680, 256, 0, stream>>>(trg_emb, W_ih, W_in, W_out,
                                          trg16, Wih16, Win16, Wout16);
    wfrag_build<<<dim3(8, 4, 128), 128, 0, stream>>>(W_hh, WF);
    h0frag<<<32, 256, 0, stream>>>(h0, h0s);

    // x_gates = trg_emb @ W_ih^T + (b_ih+b_hh) -> fp32 xgt[t][j*4+g][b]
    gemm_mfma_bt<false, true, float><<<dim3(32, 64), 256, 0, stream>>>(
        trg16, trg16, Wih16, xgt, 8192, 4096, 1024, 1024, b_ih, b_hh);

    // persistent LSTM scan (single launch; writes lstm16, hT, cT)
    lstm_scan10<<<256, 512, 0, stream>>>(xgt, WF, c0, h0s, ring,
                                         hT, cT, lstm16, bar);

    // q = lstm_out @ W_in^T (bf16 MFMA, fp32 out)
    gemm_mfma_bt<false, false, float><<<dim3(8, 64), 256, 0, stream>>>(
        lstm16, lstm16, Win16, q, 8192, 1024, 1024, 1024, nullptr, nullptr);

    // scores[b] = q[b] @ ctx[b]^T (split-precision MFMA, fp32-equivalent)
    scores_mfma<<<dim3(2, 1, 64), 256, 0, stream>>>(q, ctx, scores);

    // masked softmax -> bf16 attention weights
    softmax_mask16<<<dim3(TT, BB, 1), 256, 0, stream>>>(scores, src_len, attn16);

    // context[b] = attn[b] @ ctx[b] (bf16 MFMA, bf16 out)
    ctxattn_mfma<<<dim3(8, 1, 64), 256, 0, stream>>>(attn16, ctx, ctxout16);

    // h_tilde = tanh([context, lstm_out] @ W_out^T)
    gemm_mfma_bt<true, false, float><<<dim3(8, 64), 256, 0, stream>>>(
        ctxout16, lstm16, Wout16, h_tilde, 8192, 1024, 2048, 1024, nullptr, nullptr);
}

// Round 17
// 963.504 us; speedup vs baseline: 1.0649x; 1.0532x over previous
//
#include <hip/hip_runtime.h>
#include <math.h>

#define BB 64
#define TT 128
#define SS 256
#define HHH 1024

typedef unsigned short u16;
typedef unsigned int u32;
typedef unsigned long long u64t;
typedef __bf16 bf16x8 __attribute__((ext_vector_type(8)));
typedef float f32x4 __attribute__((ext_vector_type(4)));
typedef u16 u16x8 __attribute__((ext_vector_type(8)));

__device__ __forceinline__ float sigmoidf_(float x) { return 1.0f / (1.0f + expf(-x)); }
__device__ __forceinline__ u16 f2bf(float f) {
    __bf16 h = (__bf16)f;
    return __builtin_bit_cast(u16, h);
}
__device__ __forceinline__ float b2f(u16 u) {
    return __builtin_bit_cast(float, (u32)u << 16);
}
template <typename OT>
__device__ __forceinline__ void stout(OT* p, float v) {
    if constexpr (sizeof(OT) == 2) *p = f2bf(v); else *p = v;
}
__device__ __forceinline__ void astore(u64t* p, u64t v) {
    __hip_atomic_store(p, v, __ATOMIC_RELAXED, __HIP_MEMORY_SCOPE_AGENT);
}
__device__ __forceinline__ int afetchadd(int* p) {
    return __hip_atomic_fetch_add(p, 1, __ATOMIC_RELAXED, __HIP_MEMORY_SCOPE_AGENT);
}
__device__ __forceinline__ int aload32(const int* p) {
    return __hip_atomic_load(p, __ATOMIC_RELAXED, __HIP_MEMORY_SCOPE_AGENT);
}
__device__ __forceinline__ void astore32(int* p, int v) {
    __hip_atomic_store(p, v, __ATOMIC_RELAXED, __HIP_MEMORY_SCOPE_AGENT);
}
// async global->LDS 16B copy (dest must be wave-uniform base + lane*16)
#define GLOAD16(gsrc, ldst)                                                      \
    __builtin_amdgcn_global_load_lds(                                            \
        (const __attribute__((address_space(1))) unsigned int*)(const void*)(gsrc), \
        (__attribute__((address_space(3))) unsigned int*)(void*)(ldst), 16, 0, 0)

// ---------------------------------------------------------------------------
// fp32 → bf16 for {W_in, W_out}
// ---------------------------------------------------------------------------
__global__ __launch_bounds__(256) void convert_winout(
    const float* __restrict__ win, const float* __restrict__ wout,
    u16* __restrict__ win16, u16* __restrict__ wout16)
{
    int b = blockIdx.x;
    const float* in;
    u16* out;
    long base;
    if (b < 512) { in = win;  out = win16;  base = (long)b * 2048; }
    else         { in = wout; out = wout16; base = (long)(b - 512) * 2048; }
    long i = base + (long)threadIdx.x * 8;
    float4 a = *(const float4*)(in + i);
    float4 c = *(const float4*)(in + i + 4);
    u16x8 o;
    o[0] = f2bf(a.x); o[1] = f2bf(a.y); o[2] = f2bf(a.z); o[3] = f2bf(a.w);
    o[4] = f2bf(c.x); o[5] = f2bf(c.y); o[6] = f2bf(c.z); o[7] = f2bf(c.w);
    *(u16x8*)(out + i) = o;
}

// ---------------------------------------------------------------------------
// W_hh fp32 -> fragment-major split-precision WF (same layout as r10-r15).
// ---------------------------------------------------------------------------
__global__ __launch_bounds__(128) void wfrag_build(const float* __restrict__ W,
                                                   u16* __restrict__ WF) {
    const int w = blockIdx.x, kq = blockIdx.y, bid = blockIdx.z;
    const int t = threadIdx.x;
    const int rh = t >> 6, lane = t & 63;
    const int rowp = bid * 32 + rh * 16 + (lane & 15);
    const int g = rowp & 3, jrow = rowp >> 2;
    const int k = kq * 256 + w * 32 + (lane >> 4) * 8;
    const float* src = W + ((size_t)(g * 1024 + jrow) << 10) + k;
    float4 v0 = *(const float4*)src;
    float4 v1 = *(const float4*)(src + 4);
    float vv[8] = {v0.x, v0.y, v0.z, v0.w, v1.x, v1.y, v1.z, v1.w};
    u16x8 hi, lo;
#pragma unroll
    for (int i = 0; i < 8; ++i) {
        u16 h = f2bf(vv[i]);
        hi[i] = h;
        lo[i] = f2bf(vv[i] - b2f(h));
    }
    size_t fr = ((((size_t)bid * 4 + kq) * 8 + w) * 2 + rh) * 2;
    *(u16x8*)(WF + fr * 512 + (size_t)lane * 8) = hi;
    *(u16x8*)(WF + (fr + 1) * 512 + (size_t)lane * 8) = lo;
}

// ---------------------------------------------------------------------------
// W_ih fp32 -> per-block fragment-major bf16 WihF (single plane).
// Block ib (0..63) owns gate-rows newr in [ib*64, ib*64+64).
// frag fr = ((ib*4+kq)*8+w)*4 + sub; lane l:
//   row = ib*64 + sub*16 + (l&15)  (newr = j*4+g), k = kq*256+w*32+(l>>4)*8.
// ---------------------------------------------------------------------------
__global__ __launch_bounds__(256) void wihfrag_build(const float* __restrict__ Wih,
                                                     u16* __restrict__ WihF) {
    const int w = blockIdx.x, kq = blockIdx.y, ib = blockIdx.z;
    const int sub = threadIdx.x >> 6;
    const int lane = threadIdx.x & 63;
    const int newr = ib * 64 + sub * 16 + (lane & 15);
    const int j = newr >> 2, g = newr & 3;
    const int k = kq * 256 + w * 32 + (lane >> 4) * 8;
    const float* src = Wih + ((size_t)(g * 1024 + j) << 10) + k;
    float4 v0 = *(const float4*)src;
    float4 v1 = *(const float4*)(src + 4);
    float vv[8] = {v0.x, v0.y, v0.z, v0.w, v1.x, v1.y, v1.z, v1.w};
    u16x8 hi;
#pragma unroll
    for (int i = 0; i < 8; ++i) hi[i] = f2bf(vv[i]);
    size_t fr = (((size_t)ib * 4 + kq) * 8 + w) * 4 + sub;
    *(u16x8*)(WihF + fr * 512 + (size_t)lane * 8) = hi;
}

// ---------------------------------------------------------------------------
// trg_emb fp32 [b][t][1024] -> frag-major bf16 trgF (B-operand layout, per
// (t, group)): fr = ((t*4+g)*4+kq)*8 + w; lane = ((k>>3)&3)*16 + (b&15).
// ---------------------------------------------------------------------------
__global__ __launch_bounds__(256) void trgfrag_build(const float* __restrict__ trg,
                                                     u16* __restrict__ trgF) {
    int i = blockIdx.x * 256 + threadIdx.x;     // 1,048,576 = 64b x 128t x 128jg
    int b = i >> 14;
    int rem = i & 16383;
    int t = rem >> 7, jg = rem & 127;
    int k = jg << 3;
    const float* src = trg + ((size_t)b * 128 + t) * 1024 + k;
    float4 v0 = *(const float4*)src;
    float4 v1 = *(const float4*)(src + 4);
    float vv[8] = {v0.x, v0.y, v0.z, v0.w, v1.x, v1.y, v1.z, v1.w};
    u16x8 hi;
#pragma unroll
    for (int e = 0; e < 8; ++e) hi[e] = f2bf(vv[e]);
    int g = b >> 4, bl = b & 15;
    int kq = k >> 8, w = (k >> 5) & 7, tr = (k >> 3) & 3;
    int lane = tr * 16 + bl;
    size_t fr = (((size_t)t * 4 + g) * 4 + kq) * 8 + w;
    *(u16x8*)(trgF + fr * 512 + (size_t)lane * 8) = hi;
}

// ---------------------------------------------------------------------------
// h0 fp32 [64 b][1024 j] -> per-GROUP fragment-major hi/lo slot (t=0 input).
// ---------------------------------------------------------------------------
__global__ __launch_bounds__(256) void h0frag(const float* __restrict__ h0,
                                              u16* __restrict__ slot) {
    int i = blockIdx.x * 256 + threadIdx.x;   // 8192 = 64 b x 128 j-groups
    int b = i >> 7, jg = i & 127;
    int j = jg << 3;
    const float* src = h0 + ((size_t)b << 10) + j;
    float4 v0 = *(const float4*)src;
    float4 v1 = *(const float4*)(src + 4);
    float vv[8] = {v0.x, v0.y, v0.z, v0.w, v1.x, v1.y, v1.z, v1.w};
    u16x8 hi, lo;
#pragma unroll
    for (int e = 0; e < 8; ++e) {
        u16 h = f2bf(vv[e]);
        hi[e] = h;
        lo[e] = f2bf(vv[e] - b2f(h));
    }
    int g = b >> 4, bl = b & 15;
    int kq = j >> 8, w = (j >> 5) & 7, tr = (j >> 3) & 3;
    int lane = tr * 16 + bl;
    size_t base = (size_t)g * 32768 + (size_t)((kq * 8 + w) * 2) * 512 + (size_t)lane * 8;
    *(u16x8*)(slot + base) = hi;
    *(u16x8*)(slot + base + 512) = lo;
}

// ---------------------------------------------------------------------------
// MFMA bf16 GEMM (A@B^T), natural C write. Staging via global_load_lds.
// ---------------------------------------------------------------------------
template <bool TANH, typename OT>
__global__ __launch_bounds__(256) void gemm_mfma_bt(
    const u16* __restrict__ A0, const u16* __restrict__ A1,
    const u16* __restrict__ B, OT* __restrict__ C,
    int M, int N, int K, int KA0)
{
    __shared__ uint4 As4[512];
    __shared__ uint4 Bs4[512];
    u16* As = (u16*)As4;
    u16* Bs = (u16*)Bs4;
    const int tid = threadIdx.x;
    const int l = tid & 63;
    const int w = tid >> 6;
    const int wm = w >> 1, wn = w & 1;
    const int tc = l & 15, tr8 = (l >> 4) << 3;
    const int m0 = blockIdx.y << 7, n0 = blockIdx.x << 7;
    f32x4 acc[4][4] = {};

    for (int k0 = 0; k0 < K; k0 += 32) {
        const u16* Ap = (k0 < KA0) ? A0 : A1;
        const int koff = (k0 < KA0) ? k0 : k0 - KA0;
#pragma unroll
        for (int r = 0; r < 2; ++r) {
            int u = tid + (r << 8);
            int row = u >> 2, q = u & 3;
            GLOAD16(Ap + (size_t)(m0 + row) * KA0 + koff + (q << 3), &As4[u]);
            GLOAD16(B + (size_t)(n0 + row) * K + k0 + (q << 3), &Bs4[u]);
        }
        __syncthreads();
        bf16x8 bfr[4];
#pragma unroll
        for (int j = 0; j < 4; ++j)
            bfr[j] = *(const bf16x8*)(Bs + ((wn << 6) + (j << 4) + tc) * 32 + tr8);
#pragma unroll
        for (int i = 0; i < 4; ++i) {
            bf16x8 af = *(const bf16x8*)(As + ((wm << 6) + (i << 4) + tc) * 32 + tr8);
#pragma unroll
            for (int j = 0; j < 4; ++j)
                acc[i][j] = __builtin_amdgcn_mfma_f32_16x16x32_bf16(af, bfr[j], acc[i][j], 0, 0, 0);
        }
        __syncthreads();
    }
#pragma unroll
    for (int j = 0; j < 4; ++j) {
        const int col = n0 + (wn << 6) + (j << 4) + tc;
#pragma unroll
        for (int i = 0; i < 4; ++i) {
#pragma unroll
            for (int v = 0; v < 4; ++v) {
                int r = m0 + (wm << 6) + (i << 4) + ((l >> 4) << 2) + v;
                float val = acc[i][j][v];
                if (TANH) val = tanhf(val);
                stout(&C[(size_t)r * N + col], val);
            }
        }
    }
}

// ---------------------------------------------------------------------------
// Persistent LSTM scan v11: r13 structure + IN-SCAN x-gates GEMM.
// W_ih slice = 64 rows x 1024 k bf16 = 128 KB = 65536 u16 in LDS (all steps).
// Per step: acc initialized by x-GEMM (trgF frags x LDS WihF frags), then
// split-precision h-MFMAs accumulate; epilogue adds bias.
// Total LDS: 128K + 17K + 1K = 146 KB (1 block/CU).
// ---------------------------------------------------------------------------
__global__ __launch_bounds__(512) void lstm_scan11(
    const u16* __restrict__ trgF, const u16* __restrict__ WihF,
    const u16* __restrict__ WF, const float* __restrict__ c0,
    const float* __restrict__ b_ih, const float* __restrict__ b_hh,
    const u16* __restrict__ h0s, u16* __restrict__ ring,
    float* __restrict__ hT, float* __restrict__ cT,
    u16* __restrict__ lstm16, int* __restrict__ bar)
{
    __shared__ u16 WihL[65536];                  // 128 KB
    __shared__ float red[4][64][17];             // 17.4 KB
    __shared__ __align__(8) u16 tileh[16][16];
    __shared__ __align__(8) u16 tilel[16][16];
    const int tid = threadIdx.x;
    const int bid = blockIdx.x;
    const int g = bid >> 6;            // group 0..3
    const int ib = bid & 63;           // block in group
    const int kg = tid >> 6, l = tid & 63;
    const int kq = kg & 3, rh = kg >> 2;
    const int j0 = ib << 4;            // 16 j per block
    const int ebl = tid & 15;          // epilogue local batch
    const int ejl = (tid >> 4) & 15;   // epilogue local j (tid<256)

    // stage W_ih frag slice -> LDS (linear copy, coalesced)
    {
        const uint4* src = (const uint4*)(WihF + (size_t)ib * 65536);
        uint4* dst = (uint4*)WihL;
        for (int i = tid; i < 8192; i += 512) dst[i] = src[i];
    }

    // W_hh fragments -> registers (32 frags)
    bf16x8 wfh[2][8], wfl[2][8];
#pragma unroll
    for (int rt = 0; rt < 2; ++rt) {
        const int R16 = ib * 4 + rh * 2 + rt;
        const int bw = R16 >> 1, rhw = R16 & 1;
#pragma unroll
        for (int w = 0; w < 8; ++w) {
            size_t fr = ((((size_t)bw * 4 + kq) * 8 + w) * 2 + rhw) * 2;
            wfh[rt][w] = *(const bf16x8*)(WF + fr * 512 + (size_t)l * 8);
            wfl[rt][w] = *(const bf16x8*)(WF + (fr + 1) * 512 + (size_t)l * 8);
        }
    }
    float cv = 0.0f, biasv[4] = {};
    if (tid < 256) {
        cv = c0[(size_t)(g * 16 + ebl) * 1024 + j0 + ejl];
#pragma unroll
        for (int g2 = 0; g2 < 4; ++g2)
            biasv[g2] = b_ih[g2 * 1024 + j0 + ejl] + b_hh[g2 * 1024 + j0 + ejl];
    }
    __syncthreads();   // WihL ready

    const int kqs = ib >> 4, ws = (ib >> 1) & 7;   // store-frag coords
    int* const gbar = bar + (g << 9);

    for (int t = 0; t < 128; ++t) {
        const u16* hin = ((t == 0) ? h0s : (ring + (size_t)(t - 1) * 131072)) + (size_t)g * 32768;
        u16* hout = ring + (size_t)t * 131072 + (size_t)g * 32768;

        // trg B-frags for this step (coalesced 1KB frag loads)
        const u16* tf = trgF + ((((size_t)t * 4 + g) * 4 + kq) * 8) * 512;
        bf16x8 tb[8];
#pragma unroll
        for (int w = 0; w < 8; ++w)
            tb[w] = *(const bf16x8*)(tf + (size_t)w * 512 + l * 8);

        f32x4 acc[2] = {};
        bf16x8 hbA[2], hbB[2];
#define LDW(HB, W)                                                                  \
        {                                                                           \
            size_t fb = (size_t)((kq * 8 + (W)) * 2) * 512 + (size_t)l * 8;         \
            HB[0] = *(const bf16x8*)(hin + fb);                                     \
            HB[1] = *(const bf16x8*)(hin + fb + 512);                               \
        }
        LDW(hbA, 0)   // issue h window-0 loads early (fly during x-GEMM)

        // x-gates GEMM: acc = Wih_frag @ trg_frag  (bf16, K=256 slice)
#pragma unroll
        for (int w = 0; w < 8; ++w) {
#pragma unroll
            for (int rt = 0; rt < 2; ++rt) {
                const u16* wp = WihL + ((((size_t)kq * 8 + w) * 4) + rh * 2 + rt) * 512;
                bf16x8 wf = *(const bf16x8*)(wp + (size_t)l * 8);
                acc[rt] = __builtin_amdgcn_mfma_f32_16x16x32_bf16(wf, tb[w], acc[rt], 0, 0, 0);
            }
        }

        // recurrent h-GEMM (split precision), accumulating on top of x part
#pragma unroll
        for (int w = 0; w < 8; w += 2) {
            LDW(hbB, w + 1)
#pragma unroll
            for (int rt = 0; rt < 2; ++rt) {
                acc[rt] = __builtin_amdgcn_mfma_f32_16x16x32_bf16(wfh[rt][w], hbA[0], acc[rt], 0, 0, 0);
                acc[rt] = __builtin_amdgcn_mfma_f32_16x16x32_bf16(wfh[rt][w], hbA[1], acc[rt], 0, 0, 0);
                acc[rt] = __builtin_amdgcn_mfma_f32_16x16x32_bf16(wfl[rt][w], hbA[0], acc[rt], 0, 0, 0);
            }
            if (w + 2 < 8) LDW(hbA, w + 2)
#pragma unroll
            for (int rt = 0; rt < 2; ++rt) {
                acc[rt] = __builtin_amdgcn_mfma_f32_16x16x32_bf16(wfh[rt][w + 1], hbB[0], acc[rt], 0, 0, 0);
                acc[rt] = __builtin_amdgcn_mfma_f32_16x16x32_bf16(wfh[rt][w + 1], hbB[1], acc[rt], 0, 0, 0);
                acc[rt] = __builtin_amdgcn_mfma_f32_16x16x32_bf16(wfl[rt][w + 1], hbB[0], acc[rt], 0, 0, 0);
            }
        }
#undef LDW

#pragma unroll
        for (int rt = 0; rt < 2; ++rt)
#pragma unroll
            for (int v = 0; v < 4; ++v)
                red[kq][(rh << 5) + (rt << 4) + ((l >> 4) << 2) + v][l & 15] = acc[rt][v];
        __syncthreads();

        // epilogue (tid<256): one (b_local=ebl, j_local=ejl) per thread
        if (tid < 256) {
            float gate[4];
#pragma unroll
            for (int g2 = 0; g2 < 4; ++g2) {
                int rr = (ejl << 2) + g2;
                gate[g2] = red[0][rr][ebl] + red[1][rr][ebl] +
                           red[2][rr][ebl] + red[3][rr][ebl] + biasv[g2];
            }
            float ii = sigmoidf_(gate[0]);
            float ff = sigmoidf_(gate[1]);
            float gg = tanhf(gate[2]);
            float oo = sigmoidf_(gate[3]);
            float cn = ff * cv + ii * gg;
            float hn = oo * tanhf(cn);
            cv = cn;
            u16 hh = f2bf(hn);
            tileh[ebl][ejl] = hh;
            tilel[ebl][ejl] = f2bf(hn - b2f(hh));
            if (t == 127) {
                hT[(size_t)(g * 16 + ebl) * 1024 + j0 + ejl] = hn;
                cT[(size_t)(g * 16 + ebl) * 1024 + j0 + ejl] = cn;
            }
        }
        __syncthreads();

        // store phase: group ring slot (8B atomics, frag layout) + lstm16
        if (tid < 128) {
            const int plane = tid >> 6, rem = tid & 63;
            const int b2 = rem >> 2, half = (rem >> 1) & 1, qq = rem & 1;
            const int lane = ((ib & 1) * 2 + half) * 16 + b2;
            const u16* tp = plane ? &tilel[b2][half * 8 + qq * 4] : &tileh[b2][half * 8 + qq * 4];
            size_t a16 = (size_t)(((kqs * 8 + ws) * 2 + plane)) * 512 + (size_t)lane * 8 + qq * 4;
            astore((u64t*)(hout + a16), *(const u64t*)tp);
            if (plane == 0) {
                int qj = rem & 3;
                *(u64t*)(lstm16 + ((size_t)(g * 16 + b2) * 128 + t) * 1024 + j0 + qj * 4) =
                    *(const u64t*)&tileh[b2][qj * 4];
            }
        }

        // group-local hierarchical barrier
        if (t < 127) {
            __syncthreads();
            if (tid == 0) {
                const int leaf = ib & 7;
                int a = afetchadd(&gbar[leaf * 16]);
                if ((a & 7) == 7) {
                    int r = afetchadd(&gbar[128]);
                    if ((r & 7) == 7) astore32(&gbar[136], t + 1);
                    while (aload32(&gbar[136]) < t + 1) __builtin_amdgcn_s_sleep(1);
                    astore32(&gbar[144 + leaf * 16], t + 1);
                } else {
                    while (aload32(&gbar[144 + leaf * 16]) < t + 1)
                        __builtin_amdgcn_s_sleep(1);
                }
            }
            __syncthreads();
        }
    }
}

// ---------------------------------------------------------------------------
// scores[b] = q[b] @ ctx[b]^T  via split-precision MFMA (fp32-equivalent).
// ---------------------------------------------------------------------------
__global__ __launch_bounds__(256) void scores_mfma(
    const float* __restrict__ q, const float* __restrict__ ctx,
    float* __restrict__ C)
{
    __shared__ u16 Ahi[4096], Alo[4096], Bhi[4096], Blo[4096];
    const int tid = threadIdx.x;
    const int l = tid & 63, w = tid >> 6;
    const int wm = w >> 1, wn = w & 1;
    const int tc = l & 15, tr8 = (l >> 4) << 3;
    const int b = blockIdx.z, n0 = blockIdx.x << 7;
    const float* A = q + (size_t)b * 131072;
    const float* B = ctx + (size_t)b * 262144;
    f32x4 acc[4][4] = {};

    for (int k0 = 0; k0 < 1024; k0 += 32) {
#pragma unroll
        for (int r = 0; r < 4; ++r) {
            int flat = r * 256 + tid;
            int row = flat >> 3, kq = (flat & 7) << 2;
            int o = row * 32 + kq;
            float4 va = *(const float4*)(A + (size_t)row * 1024 + k0 + kq);
            u16 a0 = f2bf(va.x), a1 = f2bf(va.y), a2 = f2bf(va.z), a3 = f2bf(va.w);
            *(ushort4*)&Ahi[o] = (ushort4){a0, a1, a2, a3};
            *(ushort4*)&Alo[o] = (ushort4){f2bf(va.x - b2f(a0)), f2bf(va.y - b2f(a1)),
                                           f2bf(va.z - b2f(a2)), f2bf(va.w - b2f(a3))};
            float4 vb = *(const float4*)(B + (size_t)(n0 + row) * 1024 + k0 + kq);
            u16 g0 = f2bf(vb.x), g1 = f2bf(vb.y), g2 = f2bf(vb.z), g3 = f2bf(vb.w);
            *(ushort4*)&Bhi[o] = (ushort4){g0, g1, g2, g3};
            *(ushort4*)&Blo[o] = (ushort4){f2bf(vb.x - b2f(g0)), f2bf(vb.y - b2f(g1)),
                                           f2bf(vb.z - b2f(g2)), f2bf(vb.w - b2f(g3))};
        }
        __syncthreads();
        bf16x8 bh[4], bl[4];
#pragma unroll
        for (int j = 0; j < 4; ++j) {
            int o = ((wn << 6) + (j << 4) + tc) * 32 + tr8;
            bh[j] = *(const bf16x8*)(Bhi + o);
            bl[j] = *(const bf16x8*)(Blo + o);
        }
#pragma unroll
        for (int i = 0; i < 4; ++i) {
            int o = ((wm << 6) + (i << 4) + tc) * 32 + tr8;
            bf16x8 ah = *(const bf16x8*)(Ahi + o);
            bf16x8 al = *(const bf16x8*)(Alo + o);
#pragma unroll
            for (int j = 0; j < 4; ++j) {
                acc[i][j] = __builtin_amdgcn_mfma_f32_16x16x32_bf16(ah, bh[j], acc[i][j], 0, 0, 0);
                acc[i][j] = __builtin_amdgcn_mfma_f32_16x16x32_bf16(ah, bl[j], acc[i][j], 0, 0, 0);
                acc[i][j] = __builtin_amdgcn_mfma_f32_16x16x32_bf16(al, bh[j], acc[i][j], 0, 0, 0);
            }
        }
        __syncthreads();
    }
#pragma unroll
    for (int j = 0; j < 4; ++j) {
        int col = n0 + (wn << 6) + (j << 4) + tc;
#pragma unroll
        for (int i = 0; i < 4; ++i)
#pragma unroll
            for (int v = 0; v < 4; ++v) {
                int r = (wm << 6) + (i << 4) + ((l >> 4) << 2) + v;
                C[(size_t)b * 32768 + (size_t)r * 256 + col] = acc[i][j][v];
            }
    }
}

// ---------------------------------------------------------------------------
// Masked softmax over S=256; fp32 scores -> bf16 attn.
// ---------------------------------------------------------------------------
__global__ __launch_bounds__(256) void softmax_mask16(
    const float* __restrict__ scores, const int* __restrict__ src_len,
    u16* __restrict__ attn16)
{
    __shared__ float red[4];
    const int b = blockIdx.y, t = blockIdx.x, s = threadIdx.x;
    const float* row = scores + ((long)b * TT + t) * SS;
    const int L = src_len[b];
    float v = (s < L) ? row[s] : -INFINITY;
    float m = v;
#pragma unroll
    for (int o = 32; o >= 1; o >>= 1) m = fmaxf(m, __shfl_xor(m, o));
    if ((s & 63) == 0) red[s >> 6] = m;
    __syncthreads();
    m = fmaxf(fmaxf(red[0], red[1]), fmaxf(red[2], red[3]));
    __syncthreads();
    float e = (s < L) ? expf(v - m) : 0.0f;
    float sum = e;
#pragma unroll
    for (int o = 32; o >= 1; o >>= 1) sum += __shfl_xor(sum, o);
    if ((s & 63) == 0) red[s >> 6] = sum;
    __syncthreads();
    sum = red[0] + red[1] + red[2] + red[3];
    attn16[((long)b * TT + t) * SS + s] = f2bf(e / sum);
}

// ---------------------------------------------------------------------------
// context[b] = attn[b] @ ctx[b]  via bf16 MFMA (B transposed in-LDS).
// ---------------------------------------------------------------------------
__global__ __launch_bounds__(256) void ctxattn_mfma(
    const u16* __restrict__ attn16, const float* __restrict__ ctx,
    u16* __restrict__ ctxout16)
{
    __shared__ u16 As[4096];
    __shared__ u16 Bs[128][40];
    const int tid = threadIdx.x;
    const int l = tid & 63, w = tid >> 6;
    const int wm = w >> 1, wn = w & 1;
    const int tc = l & 15, tr8 = (l >> 4) << 3;
    const int b = blockIdx.z, n0 = blockIdx.x << 7;
    f32x4 acc[4][4] = {};

    for (int k0 = 0; k0 < 256; k0 += 32) {
        {
            int row = tid >> 1, off = (tid & 1) << 4;
            const u16* src = attn16 + (size_t)b * 32768 + (size_t)row * 256 + k0 + off;
            *(uint4*)&As[row * 32 + off] = *(const uint4*)src;
            *(uint4*)&As[row * 32 + off + 8] = *(const uint4*)(src + 8);
        }
#pragma unroll
        for (int p = 0; p < 4; ++p) {
            int flat = p * 256 + tid;
            int s = flat >> 5, hc = flat & 31;
            float4 v = *(const float4*)(ctx + (size_t)b * 262144 +
                                        (size_t)(k0 + s) * 1024 + n0 + (hc << 2));
            Bs[(hc << 2) + 0][s] = f2bf(v.x);
            Bs[(hc << 2) + 1][s] = f2bf(v.y);
            Bs[(hc << 2) + 2][s] = f2bf(v.z);
            Bs[(hc << 2) + 3][s] = f2bf(v.w);
        }
        __syncthreads();
        bf16x8 bfr[4];
#pragma unroll
        for (int j = 0; j < 4; ++j)
            bfr[j] = *(const bf16x8*)&Bs[(wn << 6) + (j << 4) + tc][tr8];
#pragma unroll
        for (int i = 0; i < 4; ++i) {
            bf16x8 af = *(const bf16x8*)(As + ((wm << 6) + (i << 4) + tc) * 32 + tr8);
#pragma unroll
            for (int j = 0; j < 4; ++j)
                acc[i][j] = __builtin_amdgcn_mfma_f32_16x16x32_bf16(af, bfr[j], acc[i][j], 0, 0, 0);
        }
        __syncthreads();
    }
#pragma unroll
    for (int j = 0; j < 4; ++j) {
        int col = n0 + (wn << 6) + (j << 4) + tc;
#pragma unroll
        for (int i = 0; i < 4; ++i)
#pragma unroll
            for (int v = 0; v < 4; ++v) {
                int r = (wm << 6) + (i << 4) + ((l >> 4) << 2) + v;
                ctxout16[((size_t)b * 128 + r) * 1024 + col] = f2bf(acc[i][j][v]);
            }
    }
}

// ---------------------------------------------------------------------------
extern "C" void kernel_launch(void* const* d_in, const int* in_sizes, int n_in,
                              void* d_out, int out_size, void* d_ws, size_t ws_size,
                              hipStream_t stream)
{
    const float* trg_emb = (const float*)d_in[0];
    const float* h0      = (const float*)d_in[1];
    const float* c0      = (const float*)d_in[2];
    const float* ctx     = (const float*)d_in[3];
    const int*   src_len = (const int*)d_in[4];
    const float* W_ih    = (const float*)d_in[5];
    const float* W_hh    = (const float*)d_in[6];
    const float* b_ih    = (const float*)d_in[7];
    const float* b_hh    = (const float*)d_in[8];
    const float* W_in    = (const float*)d_in[9];
    const float* W_out   = (const float*)d_in[10];

    float* out = (float*)d_out;
    float* h_tilde = out;                          // [B,T,H]
    float* hT = out + (size_t)BB * TT * HHH;       // [1,B,H]
    float* cT = hT + (size_t)BB * HHH;             // [1,B,H]

    char* w = (char*)d_ws;
    auto take = [&](size_t bytes) { void* p = w; w += (bytes + 255) & ~(size_t)255; return p; };
    u16* ring   = (u16*)take(33554432ull);         // 128 x 256 KB h ring
    u16* h0s    = (u16*)take(262144ull);           // 4-group frag slot for t=0
    u16* trgF   = (u16*)take(16777216ull);         // trg fragment layout
    u16* WihF   = (u16*)take(8388608ull);          // W_ih fragment layout
    u16* WF     = (u16*)take(16777216ull);         // W_hh fragment layout
    u16* lstm16 = (u16*)take(8388608ull * 2);
    u16* Win16  = (u16*)take(1048576ull * 2);
    u16* Wout16 = (u16*)take(2097152ull * 2);
    int* bar    = (int*)take(8192);
    char* regionB = w;
    float* q        = (float*)regionB;                          // 33.55 MB
    float* scores   = (float*)(regionB + 33554432ull);          //  8.39 MB
    u16*   attn16   = (u16*)(regionB + 41943040ull);            //  4.19 MB
    u16*   ctxout16 = (u16*)(regionB + 46137344ull);            // 16.78 MB

    // barrier counters must start at 0 every call
    hipMemsetAsync(bar, 0, 8192, stream);

    // prep: conversions + fragment builds
    convert_winout<<<1536, 256, 0, stream>>>(W_in, W_out, Win16, Wout16);
    wfrag_build<<<dim3(8, 4, 128), 128, 0, stream>>>(W_hh, WF);
    wihfrag_build<<<dim3(8, 4, 64), 256, 0, stream>>>(W_ih, WihF);
    trgfrag_build<<<4096, 256, 0, stream>>>(trg_emb, trgF);
    h0frag<<<32, 256, 0, stream>>>(h0, h0s);

    // persistent LSTM scan with fused x-gates (writes lstm16, hT, cT)
    lstm_scan11<<<256, 512, 0, stream>>>(trgF, WihF, WF, c0, b_ih, b_hh,
                                         h0s, ring, hT, cT, lstm16, bar);

    // q = lstm_out @ W_in^T (bf16 MFMA, fp32 out)
    gemm_mfma_bt<false, float><<<dim3(8, 64), 256, 0, stream>>>(
        lstm16, lstm16, Win16, q, 8192, 1024, 1024, 1024);

    // scores[b] = q[b] @ ctx[b]^T (split-precision MFMA, fp32-equivalent)
    scores_mfma<<<dim3(2, 1, 64), 256, 0, stream>>>(q, ctx, scores);

    // masked softmax -> bf16 attention weights
    softmax_mask16<<<dim3(TT, BB, 1), 256, 0, stream>>>(scores, src_len, attn16);

    // context[b] = attn[b] @ ctx[b] (bf16 MFMA, bf16 out)
    ctxattn_mfma<<<dim3(8, 1, 64), 256, 0, stream>>>(attn16, ctx, ctxout16);

    // h_tilde = tanh([context, lstm_out] @ W_out^T)
    gemm_mfma_bt<true, float><<<dim3(8, 64), 256, 0, stream>>>(
        ctxout16, lstm16, Wout16, h_tilde, 8192, 1024, 2048, 1024);
}

// Round 18
// 858.014 us; speedup vs baseline: 1.1959x; 1.1229x over previous
//
#include <hip/hip_runtime.h>
#include <math.h>

#define BB 64
#define TT 128
#define SS 256
#define HHH 1024

typedef unsigned short u16;
typedef unsigned int u32;
typedef unsigned long long u64t;
typedef __bf16 bf16x8 __attribute__((ext_vector_type(8)));
typedef float f32x4 __attribute__((ext_vector_type(4)));
typedef u16 u16x8 __attribute__((ext_vector_type(8)));

__device__ __forceinline__ float sigmoidf_(float x) { return 1.0f / (1.0f + expf(-x)); }
__device__ __forceinline__ u16 f2bf(float f) {
    __bf16 h = (__bf16)f;
    return __builtin_bit_cast(u16, h);
}
__device__ __forceinline__ float b2f(u16 u) {
    return __builtin_bit_cast(float, (u32)u << 16);
}
template <typename OT>
__device__ __forceinline__ void stout(OT* p, float v) {
    if constexpr (sizeof(OT) == 2) *p = f2bf(v); else *p = v;
}
__device__ __forceinline__ void astore(u64t* p, u64t v) {
    __hip_atomic_store(p, v, __ATOMIC_RELAXED, __HIP_MEMORY_SCOPE_AGENT);
}
__device__ __forceinline__ int afetchadd(int* p) {
    return __hip_atomic_fetch_add(p, 1, __ATOMIC_RELAXED, __HIP_MEMORY_SCOPE_AGENT);
}
__device__ __forceinline__ int aload32(const int* p) {
    return __hip_atomic_load(p, __ATOMIC_RELAXED, __HIP_MEMORY_SCOPE_AGENT);
}
__device__ __forceinline__ void astore32(int* p, int v) {
    __hip_atomic_store(p, v, __ATOMIC_RELAXED, __HIP_MEMORY_SCOPE_AGENT);
}
// async global->LDS 16B copy (dest must be wave-uniform base + lane*16)
#define GLOAD16(gsrc, ldst)                                                      \
    __builtin_amdgcn_global_load_lds(                                            \
        (const __attribute__((address_space(1))) unsigned int*)(const void*)(gsrc), \
        (__attribute__((address_space(3))) unsigned int*)(void*)(ldst), 16, 0, 0)

// ---------------------------------------------------------------------------
// Fused elementwise prep: trgfrag (4096 blocks) + convert W_in/W_out (1536)
// + h0frag (32). Flat grid 5664 x 256 thr.
// ---------------------------------------------------------------------------
__global__ __launch_bounds__(256) void prep_misc(
    const float* __restrict__ trg, u16* __restrict__ trgF,
    const float* __restrict__ win, const float* __restrict__ wout,
    u16* __restrict__ win16, u16* __restrict__ wout16,
    const float* __restrict__ h0, u16* __restrict__ slot)
{
    const int blk = blockIdx.x;
    if (blk < 4096) {
        // trg_emb fp32 [b][t][1024] -> frag-major bf16 trgF
        int i = blk * 256 + threadIdx.x;
        int b = i >> 14;
        int rem = i & 16383;
        int t = rem >> 7, jg = rem & 127;
        int k = jg << 3;
        const float* src = trg + ((size_t)b * 128 + t) * 1024 + k;
        float4 v0 = *(const float4*)src;
        float4 v1 = *(const float4*)(src + 4);
        float vv[8] = {v0.x, v0.y, v0.z, v0.w, v1.x, v1.y, v1.z, v1.w};
        u16x8 hi;
#pragma unroll
        for (int e = 0; e < 8; ++e) hi[e] = f2bf(vv[e]);
        int g = b >> 4, bl = b & 15;
        int kq = k >> 8, w = (k >> 5) & 7, tr = (k >> 3) & 3;
        int lane = tr * 16 + bl;
        size_t fr = (((size_t)t * 4 + g) * 4 + kq) * 8 + w;
        *(u16x8*)(trgF + fr * 512 + (size_t)lane * 8) = hi;
    } else if (blk < 5632) {
        // W_in / W_out fp32 -> bf16
        int b = blk - 4096;
        const float* in;
        u16* out;
        long base;
        if (b < 512) { in = win;  out = win16;  base = (long)b * 2048; }
        else         { in = wout; out = wout16; base = (long)(b - 512) * 2048; }
        long i = base + (long)threadIdx.x * 8;
        float4 a = *(const float4*)(in + i);
        float4 c = *(const float4*)(in + i + 4);
        u16x8 o;
        o[0] = f2bf(a.x); o[1] = f2bf(a.y); o[2] = f2bf(a.z); o[3] = f2bf(a.w);
        o[4] = f2bf(c.x); o[5] = f2bf(c.y); o[6] = f2bf(c.z); o[7] = f2bf(c.w);
        *(u16x8*)(out + i) = o;
    } else {
        // h0 fp32 -> per-GROUP fragment-major hi/lo slot
        int i = (blk - 5632) * 256 + threadIdx.x;
        int b = i >> 7, jg = i & 127;
        int j = jg << 3;
        const float* src = h0 + ((size_t)b << 10) + j;
        float4 v0 = *(const float4*)src;
        float4 v1 = *(const float4*)(src + 4);
        float vv[8] = {v0.x, v0.y, v0.z, v0.w, v1.x, v1.y, v1.z, v1.w};
        u16x8 hi, lo;
#pragma unroll
        for (int e = 0; e < 8; ++e) {
            u16 h = f2bf(vv[e]);
            hi[e] = h;
            lo[e] = f2bf(vv[e] - b2f(h));
        }
        int g = b >> 4, bl = b & 15;
        int kq = j >> 8, w = (j >> 5) & 7, tr = (j >> 3) & 3;
        int lane = tr * 16 + bl;
        size_t base = (size_t)g * 32768 + (size_t)((kq * 8 + w) * 2) * 512 + (size_t)lane * 8;
        *(u16x8*)(slot + base) = hi;
        *(u16x8*)(slot + base + 512) = lo;
    }
}

// ---------------------------------------------------------------------------
// W_hh fp32 -> fragment-major split-precision WF (same layout as r10-r17).
// ---------------------------------------------------------------------------
__global__ __launch_bounds__(128) void wfrag_build(const float* __restrict__ W,
                                                   u16* __restrict__ WF) {
    const int w = blockIdx.x, kq = blockIdx.y, bid = blockIdx.z;
    const int t = threadIdx.x;
    const int rh = t >> 6, lane = t & 63;
    const int rowp = bid * 32 + rh * 16 + (lane & 15);
    const int g = rowp & 3, jrow = rowp >> 2;
    const int k = kq * 256 + w * 32 + (lane >> 4) * 8;
    const float* src = W + ((size_t)(g * 1024 + jrow) << 10) + k;
    float4 v0 = *(const float4*)src;
    float4 v1 = *(const float4*)(src + 4);
    float vv[8] = {v0.x, v0.y, v0.z, v0.w, v1.x, v1.y, v1.z, v1.w};
    u16x8 hi, lo;
#pragma unroll
    for (int i = 0; i < 8; ++i) {
        u16 h = f2bf(vv[i]);
        hi[i] = h;
        lo[i] = f2bf(vv[i] - b2f(h));
    }
    size_t fr = ((((size_t)bid * 4 + kq) * 8 + w) * 2 + rh) * 2;
    *(u16x8*)(WF + fr * 512 + (size_t)lane * 8) = hi;
    *(u16x8*)(WF + (fr + 1) * 512 + (size_t)lane * 8) = lo;
}

// ---------------------------------------------------------------------------
// W_ih fp32 -> per-block fragment-major bf16 WihF (single plane).
// ---------------------------------------------------------------------------
__global__ __launch_bounds__(256) void wihfrag_build(const float* __restrict__ Wih,
                                                     u16* __restrict__ WihF) {
    const int w = blockIdx.x, kq = blockIdx.y, ib = blockIdx.z;
    const int sub = threadIdx.x >> 6;
    const int lane = threadIdx.x & 63;
    const int newr = ib * 64 + sub * 16 + (lane & 15);
    const int j = newr >> 2, g = newr & 3;
    const int k = kq * 256 + w * 32 + (lane >> 4) * 8;
    const float* src = Wih + ((size_t)(g * 1024 + j) << 10) + k;
    float4 v0 = *(const float4*)src;
    float4 v1 = *(const float4*)(src + 4);
    float vv[8] = {v0.x, v0.y, v0.z, v0.w, v1.x, v1.y, v1.z, v1.w};
    u16x8 hi;
#pragma unroll
    for (int i = 0; i < 8; ++i) hi[i] = f2bf(vv[i]);
    size_t fr = (((size_t)ib * 4 + kq) * 8 + w) * 4 + sub;
    *(u16x8*)(WihF + fr * 512 + (size_t)lane * 8) = hi;
}

// ---------------------------------------------------------------------------
// MFMA bf16 GEMM (A@B^T), natural C write. Staging via global_load_lds.
// ---------------------------------------------------------------------------
template <bool TANH, typename OT>
__global__ __launch_bounds__(256) void gemm_mfma_bt(
    const u16* __restrict__ A0, const u16* __restrict__ A1,
    const u16* __restrict__ B, OT* __restrict__ C,
    int M, int N, int K, int KA0)
{
    __shared__ uint4 As4[512];
    __shared__ uint4 Bs4[512];
    u16* As = (u16*)As4;
    u16* Bs = (u16*)Bs4;
    const int tid = threadIdx.x;
    const int l = tid & 63;
    const int w = tid >> 6;
    const int wm = w >> 1, wn = w & 1;
    const int tc = l & 15, tr8 = (l >> 4) << 3;
    const int m0 = blockIdx.y << 7, n0 = blockIdx.x << 7;
    f32x4 acc[4][4] = {};

    for (int k0 = 0; k0 < K; k0 += 32) {
        const u16* Ap = (k0 < KA0) ? A0 : A1;
        const int koff = (k0 < KA0) ? k0 : k0 - KA0;
#pragma unroll
        for (int r = 0; r < 2; ++r) {
            int u = tid + (r << 8);
            int row = u >> 2, q = u & 3;
            GLOAD16(Ap + (size_t)(m0 + row) * KA0 + koff + (q << 3), &As4[u]);
            GLOAD16(B + (size_t)(n0 + row) * K + k0 + (q << 3), &Bs4[u]);
        }
        __syncthreads();
        bf16x8 bfr[4];
#pragma unroll
        for (int j = 0; j < 4; ++j)
            bfr[j] = *(const bf16x8*)(Bs + ((wn << 6) + (j << 4) + tc) * 32 + tr8);
#pragma unroll
        for (int i = 0; i < 4; ++i) {
            bf16x8 af = *(const bf16x8*)(As + ((wm << 6) + (i << 4) + tc) * 32 + tr8);
#pragma unroll
            for (int j = 0; j < 4; ++j)
                acc[i][j] = __builtin_amdgcn_mfma_f32_16x16x32_bf16(af, bfr[j], acc[i][j], 0, 0, 0);
        }
        __syncthreads();
    }
#pragma unroll
    for (int j = 0; j < 4; ++j) {
        const int col = n0 + (wn << 6) + (j << 4) + tc;
#pragma unroll
        for (int i = 0; i < 4; ++i) {
#pragma unroll
            for (int v = 0; v < 4; ++v) {
                int r = m0 + (wm << 6) + (i << 4) + ((l >> 4) << 2) + v;
                float val = acc[i][j][v];
                if (TANH) val = tanhf(val);
                stout(&C[(size_t)r * N + col], val);
            }
        }
    }
}

// ---------------------------------------------------------------------------
// Persistent LSTM scan v12 = r17's scan11 with a flattened barrier release:
// the 8th leaf-closer at the root stores t+1 DIRECTLY into all 8 leafgen
// lines (removes the gen word + closer poll hop: 4 RTs -> 3 RTs).
// Math chain identical -> bit-identical output.
// ---------------------------------------------------------------------------
__global__ __launch_bounds__(512) void lstm_scan12(
    const u16* __restrict__ trgF, const u16* __restrict__ WihF,
    const u16* __restrict__ WF, const float* __restrict__ c0,
    const float* __restrict__ b_ih, const float* __restrict__ b_hh,
    const u16* __restrict__ h0s, u16* __restrict__ ring,
    float* __restrict__ hT, float* __restrict__ cT,
    u16* __restrict__ lstm16, int* __restrict__ bar)
{
    __shared__ u16 WihL[65536];                  // 128 KB
    __shared__ float red[4][64][17];             // 17.4 KB
    __shared__ __align__(8) u16 tileh[16][16];
    __shared__ __align__(8) u16 tilel[16][16];
    const int tid = threadIdx.x;
    const int bid = blockIdx.x;
    const int g = bid >> 6;            // group 0..3
    const int ib = bid & 63;           // block in group
    const int kg = tid >> 6, l = tid & 63;
    const int kq = kg & 3, rh = kg >> 2;
    const int j0 = ib << 4;            // 16 j per block
    const int ebl = tid & 15;          // epilogue local batch
    const int ejl = (tid >> 4) & 15;   // epilogue local j (tid<256)

    // stage W_ih frag slice -> LDS (linear copy, coalesced)
    {
        const uint4* src = (const uint4*)(WihF + (size_t)ib * 65536);
        uint4* dst = (uint4*)WihL;
        for (int i = tid; i < 8192; i += 512) dst[i] = src[i];
    }

    // W_hh fragments -> registers (32 frags)
    bf16x8 wfh[2][8], wfl[2][8];
#pragma unroll
    for (int rt = 0; rt < 2; ++rt) {
        const int R16 = ib * 4 + rh * 2 + rt;
        const int bw = R16 >> 1, rhw = R16 & 1;
#pragma unroll
        for (int w = 0; w < 8; ++w) {
            size_t fr = ((((size_t)bw * 4 + kq) * 8 + w) * 2 + rhw) * 2;
            wfh[rt][w] = *(const bf16x8*)(WF + fr * 512 + (size_t)l * 8);
            wfl[rt][w] = *(const bf16x8*)(WF + (fr + 1) * 512 + (size_t)l * 8);
        }
    }
    float cv = 0.0f, biasv[4] = {};
    if (tid < 256) {
        cv = c0[(size_t)(g * 16 + ebl) * 1024 + j0 + ejl];
#pragma unroll
        for (int g2 = 0; g2 < 4; ++g2)
            biasv[g2] = b_ih[g2 * 1024 + j0 + ejl] + b_hh[g2 * 1024 + j0 + ejl];
    }
    __syncthreads();   // WihL ready

    const int kqs = ib >> 4, ws = (ib >> 1) & 7;   // store-frag coords
    int* const gbar = bar + (g << 9);

    for (int t = 0; t < 128; ++t) {
        const u16* hin = ((t == 0) ? h0s : (ring + (size_t)(t - 1) * 131072)) + (size_t)g * 32768;
        u16* hout = ring + (size_t)t * 131072 + (size_t)g * 32768;

        // trg B-frags for this step (coalesced 1KB frag loads)
        const u16* tf = trgF + ((((size_t)t * 4 + g) * 4 + kq) * 8) * 512;
        bf16x8 tb[8];
#pragma unroll
        for (int w = 0; w < 8; ++w)
            tb[w] = *(const bf16x8*)(tf + (size_t)w * 512 + l * 8);

        f32x4 acc[2] = {};
        bf16x8 hbA[2], hbB[2];
#define LDW(HB, W)                                                                  \
        {                                                                           \
            size_t fb = (size_t)((kq * 8 + (W)) * 2) * 512 + (size_t)l * 8;         \
            HB[0] = *(const bf16x8*)(hin + fb);                                     \
            HB[1] = *(const bf16x8*)(hin + fb + 512);                               \
        }
        LDW(hbA, 0)   // issue h window-0 loads early (fly during x-GEMM)

        // x-gates GEMM: acc = Wih_frag @ trg_frag  (bf16, K=256 slice)
#pragma unroll
        for (int w = 0; w < 8; ++w) {
#pragma unroll
            for (int rt = 0; rt < 2; ++rt) {
                const u16* wp = WihL + ((((size_t)kq * 8 + w) * 4) + rh * 2 + rt) * 512;
                bf16x8 wf = *(const bf16x8*)(wp + (size_t)l * 8);
                acc[rt] = __builtin_amdgcn_mfma_f32_16x16x32_bf16(wf, tb[w], acc[rt], 0, 0, 0);
            }
        }

        // recurrent h-GEMM (split precision), accumulating on top of x part
#pragma unroll
        for (int w = 0; w < 8; w += 2) {
            LDW(hbB, w + 1)
#pragma unroll
            for (int rt = 0; rt < 2; ++rt) {
                acc[rt] = __builtin_amdgcn_mfma_f32_16x16x32_bf16(wfh[rt][w], hbA[0], acc[rt], 0, 0, 0);
                acc[rt] = __builtin_amdgcn_mfma_f32_16x16x32_bf16(wfh[rt][w], hbA[1], acc[rt], 0, 0, 0);
                acc[rt] = __builtin_amdgcn_mfma_f32_16x16x32_bf16(wfl[rt][w], hbA[0], acc[rt], 0, 0, 0);
            }
            if (w + 2 < 8) LDW(hbA, w + 2)
#pragma unroll
            for (int rt = 0; rt < 2; ++rt) {
                acc[rt] = __builtin_amdgcn_mfma_f32_16x16x32_bf16(wfh[rt][w + 1], hbB[0], acc[rt], 0, 0, 0);
                acc[rt] = __builtin_amdgcn_mfma_f32_16x16x32_bf16(wfh[rt][w + 1], hbB[1], acc[rt], 0, 0, 0);
                acc[rt] = __builtin_amdgcn_mfma_f32_16x16x32_bf16(wfl[rt][w + 1], hbB[0], acc[rt], 0, 0, 0);
            }
        }
#undef LDW

#pragma unroll
        for (int rt = 0; rt < 2; ++rt)
#pragma unroll
            for (int v = 0; v < 4; ++v)
                red[kq][(rh << 5) + (rt << 4) + ((l >> 4) << 2) + v][l & 15] = acc[rt][v];
        __syncthreads();

        // epilogue (tid<256): one (b_local=ebl, j_local=ejl) per thread
        if (tid < 256) {
            float gate[4];
#pragma unroll
            for (int g2 = 0; g2 < 4; ++g2) {
                int rr = (ejl << 2) + g2;
                gate[g2] = red[0][rr][ebl] + red[1][rr][ebl] +
                           red[2][rr][ebl] + red[3][rr][ebl] + biasv[g2];
            }
            float ii = sigmoidf_(gate[0]);
            float ff = sigmoidf_(gate[1]);
            float gg = tanhf(gate[2]);
            float oo = sigmoidf_(gate[3]);
            float cn = ff * cv + ii * gg;
            float hn = oo * tanhf(cn);
            cv = cn;
            u16 hh = f2bf(hn);
            tileh[ebl][ejl] = hh;
            tilel[ebl][ejl] = f2bf(hn - b2f(hh));
            if (t == 127) {
                hT[(size_t)(g * 16 + ebl) * 1024 + j0 + ejl] = hn;
                cT[(size_t)(g * 16 + ebl) * 1024 + j0 + ejl] = cn;
            }
        }
        __syncthreads();

        // store phase: group ring slot (8B atomics, frag layout) + lstm16
        if (tid < 128) {
            const int plane = tid >> 6, rem = tid & 63;
            const int b2 = rem >> 2, half = (rem >> 1) & 1, qq = rem & 1;
            const int lane = ((ib & 1) * 2 + half) * 16 + b2;
            const u16* tp = plane ? &tilel[b2][half * 8 + qq * 4] : &tileh[b2][half * 8 + qq * 4];
            size_t a16 = (size_t)(((kqs * 8 + ws) * 2 + plane)) * 512 + (size_t)lane * 8 + qq * 4;
            astore((u64t*)(hout + a16), *(const u64t*)tp);
            if (plane == 0) {
                int qj = rem & 3;
                *(u64t*)(lstm16 + ((size_t)(g * 16 + b2) * 128 + t) * 1024 + j0 + qj * 4) =
                    *(const u64t*)&tileh[b2][qj * 4];
            }
        }

        // group-local barrier, flattened release (3 coherence RTs)
        if (t < 127) {
            __syncthreads();   // drains vmem: ring stores memory-side-visible
            if (tid == 0) {
                const int leaf = ib & 7;
                int a = afetchadd(&gbar[leaf * 16]);
                if ((a & 7) == 7) {
                    int r = afetchadd(&gbar[128]);
                    if ((r & 7) == 7) {
#pragma unroll
                        for (int q = 0; q < 8; ++q)
                            astore32(&gbar[144 + q * 16], t + 1);
                    }
                }
                while (aload32(&gbar[144 + leaf * 16]) < t + 1)
                    __builtin_amdgcn_s_sleep(1);
            }
            __syncthreads();
        }
    }
}

// ---------------------------------------------------------------------------
// scores[b] = q[b] @ ctx[b]^T  via split-precision MFMA (fp32-equivalent).
// ---------------------------------------------------------------------------
__global__ __launch_bounds__(256) void scores_mfma(
    const float* __restrict__ q, const float* __restrict__ ctx,
    float* __restrict__ C)
{
    __shared__ u16 Ahi[4096], Alo[4096], Bhi[4096], Blo[4096];
    const int tid = threadIdx.x;
    const int l = tid & 63, w = tid >> 6;
    const int wm = w >> 1, wn = w & 1;
    const int tc = l & 15, tr8 = (l >> 4) << 3;
    const int b = blockIdx.z, n0 = blockIdx.x << 7;
    const float* A = q + (size_t)b * 131072;
    const float* B = ctx + (size_t)b * 262144;
    f32x4 acc[4][4] = {};

    for (int k0 = 0; k0 < 1024; k0 += 32) {
#pragma unroll
        for (int r = 0; r < 4; ++r) {
            int flat = r * 256 + tid;
            int row = flat >> 3, kq = (flat & 7) << 2;
            int o = row * 32 + kq;
            float4 va = *(const float4*)(A + (size_t)row * 1024 + k0 + kq);
            u16 a0 = f2bf(va.x), a1 = f2bf(va.y), a2 = f2bf(va.z), a3 = f2bf(va.w);
            *(ushort4*)&Ahi[o] = (ushort4){a0, a1, a2, a3};
            *(ushort4*)&Alo[o] = (ushort4){f2bf(va.x - b2f(a0)), f2bf(va.y - b2f(a1)),
                                           f2bf(va.z - b2f(a2)), f2bf(va.w - b2f(a3))};
            float4 vb = *(const float4*)(B + (size_t)(n0 + row) * 1024 + k0 + kq);
            u16 g0 = f2bf(vb.x), g1 = f2bf(vb.y), g2 = f2bf(vb.z), g3 = f2bf(vb.w);
            *(ushort4*)&Bhi[o] = (ushort4){g0, g1, g2, g3};
            *(ushort4*)&Blo[o] = (ushort4){f2bf(vb.x - b2f(g0)), f2bf(vb.y - b2f(g1)),
                                           f2bf(vb.z - b2f(g2)), f2bf(vb.w - b2f(g3))};
        }
        __syncthreads();
        bf16x8 bh[4], bl[4];
#pragma unroll
        for (int j = 0; j < 4; ++j) {
            int o = ((wn << 6) + (j << 4) + tc) * 32 + tr8;
            bh[j] = *(const bf16x8*)(Bhi + o);
            bl[j] = *(const bf16x8*)(Blo + o);
        }
#pragma unroll
        for (int i = 0; i < 4; ++i) {
            int o = ((wm << 6) + (i << 4) + tc) * 32 + tr8;
            bf16x8 ah = *(const bf16x8*)(Ahi + o);
            bf16x8 al = *(const bf16x8*)(Alo + o);
#pragma unroll
            for (int j = 0; j < 4; ++j) {
                acc[i][j] = __builtin_amdgcn_mfma_f32_16x16x32_bf16(ah, bh[j], acc[i][j], 0, 0, 0);
                acc[i][j] = __builtin_amdgcn_mfma_f32_16x16x32_bf16(ah, bl[j], acc[i][j], 0, 0, 0);
                acc[i][j] = __builtin_amdgcn_mfma_f32_16x16x32_bf16(al, bh[j], acc[i][j], 0, 0, 0);
            }
        }
        __syncthreads();
    }
#pragma unroll
    for (int j = 0; j < 4; ++j) {
        int col = n0 + (wn << 6) + (j << 4) + tc;
#pragma unroll
        for (int i = 0; i < 4; ++i)
#pragma unroll
            for (int v = 0; v < 4; ++v) {
                int r = (wm << 6) + (i << 4) + ((l >> 4) << 2) + v;
                C[(size_t)b * 32768 + (size_t)r * 256 + col] = acc[i][j][v];
            }
    }
}

// ---------------------------------------------------------------------------
// Masked softmax over S=256; fp32 scores -> bf16 attn.
// ---------------------------------------------------------------------------
__global__ __launch_bounds__(256) void softmax_mask16(
    const float* __restrict__ scores, const int* __restrict__ src_len,
    u16* __restrict__ attn16)
{
    __shared__ float red[4];
    const int b = blockIdx.y, t = blockIdx.x, s = threadIdx.x;
    const float* row = scores + ((long)b * TT + t) * SS;
    const int L = src_len[b];
    float v = (s < L) ? row[s] : -INFINITY;
    float m = v;
#pragma unroll
    for (int o = 32; o >= 1; o >>= 1) m = fmaxf(m, __shfl_xor(m, o));
    if ((s & 63) == 0) red[s >> 6] = m;
    __syncthreads();
    m = fmaxf(fmaxf(red[0], red[1]), fmaxf(red[2], red[3]));
    __syncthreads();
    float e = (s < L) ? expf(v - m) : 0.0f;
    float sum = e;
#pragma unroll
    for (int o = 32; o >= 1; o >>= 1) sum += __shfl_xor(sum, o);
    if ((s & 63) == 0) red[s >> 6] = sum;
    __syncthreads();
    sum = red[0] + red[1] + red[2] + red[3];
    attn16[((long)b * TT + t) * SS + s] = f2bf(e / sum);
}

// ---------------------------------------------------------------------------
// context[b] = attn[b] @ ctx[b]  via bf16 MFMA (B transposed in-LDS).
// ---------------------------------------------------------------------------
__global__ __launch_bounds__(256) void ctxattn_mfma(
    const u16* __restrict__ attn16, const float* __restrict__ ctx,
    u16* __restrict__ ctxout16)
{
    __shared__ u16 As[4096];
    __shared__ u16 Bs[128][40];
    const int tid = threadIdx.x;
    const int l = tid & 63, w = tid >> 6;
    const int wm = w >> 1, wn = w & 1;
    const int tc = l & 15, tr8 = (l >> 4) << 3;
    const int b = blockIdx.z, n0 = blockIdx.x << 7;
    f32x4 acc[4][4] = {};

    for (int k0 = 0; k0 < 256; k0 += 32) {
        {
            int row = tid >> 1, off = (tid & 1) << 4;
            const u16* src = attn16 + (size_t)b * 32768 + (size_t)row * 256 + k0 + off;
            *(uint4*)&As[row * 32 + off] = *(const uint4*)src;
            *(uint4*)&As[row * 32 + off + 8] = *(const uint4*)(src + 8);
        }
#pragma unroll
        for (int p = 0; p < 4; ++p) {
            int flat = p * 256 + tid;
            int s = flat >> 5, hc = flat & 31;
            float4 v = *(const float4*)(ctx + (size_t)b * 262144 +
                                        (size_t)(k0 + s) * 1024 + n0 + (hc << 2));
            Bs[(hc << 2) + 0][s] = f2bf(v.x);
            Bs[(hc << 2) + 1][s] = f2bf(v.y);
            Bs[(hc << 2) + 2][s] = f2bf(v.z);
            Bs[(hc << 2) + 3][s] = f2bf(v.w);
        }
        __syncthreads();
        bf16x8 bfr[4];
#pragma unroll
        for (int j = 0; j < 4; ++j)
            bfr[j] = *(const bf16x8*)&Bs[(wn << 6) + (j << 4) + tc][tr8];
#pragma unroll
        for (int i = 0; i < 4; ++i) {
            bf16x8 af = *(const bf16x8*)(As + ((wm << 6) + (i << 4) + tc) * 32 + tr8);
#pragma unroll
            for (int j = 0; j < 4; ++j)
                acc[i][j] = __builtin_amdgcn_mfma_f32_16x16x32_bf16(af, bfr[j], acc[i][j], 0, 0, 0);
        }
        __syncthreads();
    }
#pragma unroll
    for (int j = 0; j < 4; ++j) {
        int col = n0 + (wn << 6) + (j << 4) + tc;
#pragma unroll
        for (int i = 0; i < 4; ++i)
#pragma unroll
            for (int v = 0; v < 4; ++v) {
                int r = (wm << 6) + (i << 4) + ((l >> 4) << 2) + v;
                ctxout16[((size_t)b * 128 + r) * 1024 + col] = f2bf(acc[i][j][v]);
            }
    }
}

// ---------------------------------------------------------------------------
extern "C" void kernel_launch(void* const* d_in, const int* in_sizes, int n_in,
                              void* d_out, int out_size, void* d_ws, size_t ws_size,
                              hipStream_t stream)
{
    const float* trg_emb = (const float*)d_in[0];
    const float* h0      = (const float*)d_in[1];
    const float* c0      = (const float*)d_in[2];
    const float* ctx     = (const float*)d_in[3];
    const int*   src_len = (const int*)d_in[4];
    const float* W_ih    = (const float*)d_in[5];
    const float* W_hh    = (const float*)d_in[6];
    const float* b_ih    = (const float*)d_in[7];
    const float* b_hh    = (const float*)d_in[8];
    const float* W_in    = (const float*)d_in[9];
    const float* W_out   = (const float*)d_in[10];

    float* out = (float*)d_out;
    float* h_tilde = out;                          // [B,T,H]
    float* hT = out + (size_t)BB * TT * HHH;       // [1,B,H]
    float* cT = hT + (size_t)BB * HHH;             // [1,B,H]

    char* w = (char*)d_ws;
    auto take = [&](size_t bytes) { void* p = w; w += (bytes + 255) & ~(size_t)255; return p; };
    u16* ring   = (u16*)take(33554432ull);         // 128 x 256 KB h ring
    u16* h0s    = (u16*)take(262144ull);           // 4-group frag slot for t=0
    u16* trgF   = (u16*)take(16777216ull);         // trg fragment layout
    u16* WihF   = (u16*)take(8388608ull);          // W_ih fragment layout
    u16* WF     = (u16*)take(16777216ull);         // W_hh fragment layout
    u16* lstm16 = (u16*)take(8388608ull * 2);
    u16* Win16  = (u16*)take(1048576ull * 2);
    u16* Wout16 = (u16*)take(2097152ull * 2);
    int* bar    = (int*)take(8192);
    char* regionB = w;
    float* q        = (float*)regionB;                          // 33.55 MB
    float* scores   = (float*)(regionB + 33554432ull);          //  8.39 MB
    u16*   attn16   = (u16*)(regionB + 41943040ull);            //  4.19 MB
    u16*   ctxout16 = (u16*)(regionB + 46137344ull);            // 16.78 MB

    // barrier counters must start at 0 every call
    hipMemsetAsync(bar, 0, 8192, stream);

    // prep: fused elementwise prep + fragment builds
    prep_misc<<<5664, 256, 0, stream>>>(trg_emb, trgF, W_in, W_out,
                                        Win16, Wout16, h0, h0s);
    wfrag_build<<<dim3(8, 4, 128), 128, 0, stream>>>(W_hh, WF);
    wihfrag_build<<<dim3(8, 4, 64), 256, 0, stream>>>(W_ih, WihF);

    // persistent LSTM scan with fused x-gates (writes lstm16, hT, cT)
    lstm_scan12<<<256, 512, 0, stream>>>(trgF, WihF, WF, c0, b_ih, b_hh,
                                         h0s, ring, hT, cT, lstm16, bar);

    // q = lstm_out @ W_in^T (bf16 MFMA, fp32 out)
    gemm_mfma_bt<false, float><<<dim3(8, 64), 256, 0, stream>>>(
        lstm16, lstm16, Win16, q, 8192, 1024, 1024, 1024);

    // scores[b] = q[b] @ ctx[b]^T (split-precision MFMA, fp32-equivalent)
    scores_mfma<<<dim3(2, 1, 64), 256, 0, stream>>>(q, ctx, scores);

    // masked softmax -> bf16 attention weights
    softmax_mask16<<<dim3(TT, BB, 1), 256, 0, stream>>>(scores, src_len, attn16);

    // context[b] = attn[b] @ ctx[b] (bf16 MFMA, bf16 out)
    ctxattn_mfma<<<dim3(8, 1, 64), 256, 0, stream>>>(attn16, ctx, ctxout16);

    // h_tilde = tanh([context, lstm_out] @ W_out^T)
    gemm_mfma_bt<true, float><<<dim3(8, 64), 256, 0, stream>>>(
        ctxout16, lstm16, Wout16, h_tilde, 8192, 1024, 2048, 1024);
}